// Round 9
// baseline (459.328 us; speedup 1.0000x reference)
//
#include <hip/hip_runtime.h>
#include <hip/hip_bf16.h>

typedef __hip_bfloat16 bf16;
typedef __attribute__((ext_vector_type(8))) short bf8v;   // 8 bf16 (4 VGPRs)
typedef __attribute__((ext_vector_type(4))) short s4v;
typedef __attribute__((ext_vector_type(4))) float f4v;
typedef __attribute__((ext_vector_type(2))) float f2v;

#define DEV __device__ __forceinline__

DEV float b2f(bf16 v){ return __bfloat162float(v); }
DEV bf16 f2b(float v){ return __float2bfloat16(v); }
DEV short f2bs(float v){ bf16 t = __float2bfloat16(v); return *reinterpret_cast<short*>(&t); }
DEV float s2f(short s){ return __uint_as_float(((unsigned int)(unsigned short)s) << 16); }
DEV float rcpf_(float x){ return __builtin_amdgcn_rcpf(x); }
DEV float sigf(float x){ return rcpf_(1.0f + __expf(-x)); }
DEV float tanhfast(float x){
  x = fminf(fmaxf(x, -15.0f), 15.0f);
  float e = __expf(-2.0f*x);
  return (1.0f - e)*rcpf_(1.0f + e);
}
// packed helpers (f2v = <2 x float>, LLVM can emit v_pk_* for these)
DEV f2v pk2(float a, float b){ f2v r; r[0]=a; r[1]=b; return r; }
DEV f2v pkmin(f2v a, float b){ return pk2(fminf(a[0],b), fminf(a[1],b)); }
DEV f2v pkmax(f2v a, float b){ return pk2(fmaxf(a[0],b), fmaxf(a[1],b)); }
DEV f2v pkexp2(f2v a){ return pk2(__builtin_amdgcn_exp2f(a[0]), __builtin_amdgcn_exp2f(a[1])); }
DEV f2v pkrcp(f2v a){ return pk2(rcpf_(a[0]), rcpf_(a[1])); }

DEV f4v mfma16(bf8v a, bf8v b, f4v c){
  return __builtin_amdgcn_mfma_f32_16x16x32_bf16(a, b, c, 0, 0, 0);
}

// ---------------------------------------------------------------------------
// K0a: dtype detector (fp32 vs bf16 inputs). flag[0]=1 -> bf16, 0 -> fp32.
// ---------------------------------------------------------------------------
__global__ void k_detect(const unsigned int* __restrict__ xw, int* __restrict__ flag){
  __shared__ int found;
  if (threadIdx.x == 0) found = 0;
  __syncthreads();
  int local = 0;
  for (int i = threadIdx.x; i < 4096; i += 256){
    unsigned int u = xw[i];
    unsigned int e = (u >> 7) & 0xFF;
    if (e >= 0x90) local = 1;
  }
  if (local) atomicOr(&found, 1);
  __syncthreads();
  if (threadIdx.x == 0) flag[0] = found ? 0 : 1;
}

// ---------------------------------------------------------------------------
// K0b: canonicalize all float inputs into a bf16 region in ws.
// ---------------------------------------------------------------------------
struct CArgs {
  const void* src[44];
  int n[44];
  int off[44];
};

__global__ void k_canon(CArgs a, const int* __restrict__ flag, bf16* __restrict__ dst){
  int id = blockIdx.y;
  int n = a.n[id];
  const void* s = a.src[id];
  bf16* d = dst + a.off[id];
  int stride = gridDim.x * blockDim.x;
  int i0 = blockIdx.x * blockDim.x + threadIdx.x;
  if (flag[0]){
    const bf16* sb = (const bf16*)s;
    for (int i = i0; i < n; i += stride) d[i] = sb[i];
  } else {
    const float* sf = (const float*)s;
    for (int i = i0; i < n; i += stride) d[i] = f2b(sf[i]);
  }
}

// ---------------------------------------------------------------------------
// K0c: prep padded operands + exp2-prescaled LSTM weights (see r4 notes).
// ---------------------------------------------------------------------------
__global__ void k_prep(const bf16* __restrict__ Wp, const bf16* __restrict__ An,
                       const bf16* __restrict__ Whh, const bf16* __restrict__ Wih,
                       const bf16* __restrict__ bih, const bf16* __restrict__ bhh,
                       bf16* __restrict__ Wpp, bf16* __restrict__ Anp,
                       bf16* __restrict__ htp, bf16* __restrict__ hb2p,
                       bf16* __restrict__ Whh_s, bf16* __restrict__ Wih_s,
                       float* __restrict__ bias_s){
  int stride = gridDim.x * blockDim.x;
  bf16 zero = f2b(0.0f);
  const float L2E = 1.44269504089f;
  for (int i = blockIdx.x*blockDim.x + threadIdx.x; i < 608768; i += stride){
    if (i < 4096){
      int row = i >> 5, col = i & 31;
      Wpp[i] = (col < 26) ? Wp[row*26 + col] : zero;
    } else if (i < 18432){
      int j = i - 4096;
      int row = j >> 7, col = j & 127;
      Anp[j] = (row < 100 && col < 100) ? An[row*100 + col] : zero;
    } else if (i < 247808){
      htp[i - 18432] = zero;
    } else if (i < 477184){
      hb2p[i - 247808] = zero;
    } else if (i < 542720){
      int j = i - 477184;
      float s = ((j >> 14) == 2) ? -2.0f*L2E : -L2E;
      Whh_s[j] = f2b(b2f(Whh[j]) * s);
    } else if (i < 608256){
      int j = i - 542720;
      float s = ((j >> 14) == 2) ? -2.0f*L2E : -L2E;
      Wih_s[j] = f2b(b2f(Wih[j]) * s);
    } else {
      int j = i - 608256;
      float s = ((j >> 7) == 2) ? -2.0f*L2E : -L2E;
      bias_s[j] = (b2f(bih[j]) + b2f(bhh[j])) * s;
    }
  }
}

// ---------------------------------------------------------------------------
// K_INAT (r5 structure + vectorized h0 writeback): fused inproj+LN -> attn.
// grid = 1600, block = 256, LDS 52736 -> 3 blocks/CU. h0 global write is a
// uint4 block-copy from h0s (was 64 scalar bf16 stores/thread).
// ---------------------------------------------------------------------------
__global__ __launch_bounds__(256,3) void k_inat(const bf16* __restrict__ x,
    const bf16* __restrict__ Wpp, const bf16* __restrict__ bp,
    const bf16* __restrict__ gp, const bf16* __restrict__ bbp,
    const bf16* __restrict__ Wqkv, const bf16* __restrict__ bqkv,
    bf16* __restrict__ h0, bf16* __restrict__ attno){
  int bn = blockIdx.x;
  int tid = threadIdx.x;
  int w = tid >> 6;
  int lane = tid & 63;
  int l15 = lane & 15, quad = lane >> 4;

  __shared__ __align__(16) short h0s[96*136];    // x-flat at P0; P panels later
  __shared__ __align__(16) short v_sh[4][32*104];// xt overlay; sw scratch; V^T

  // P0: stage x flat (96x26 = 312 uint4) into h0s (dead region)
  {
    const uint4* src = (const uint4*)(x + bn*2496);
    uint4* dst = (uint4*)h0s;
    for (int u = tid; u < 312; u += 256) dst[u] = src[u];
  }
  __syncthreads();
  // P1: build xt (96x40, cols 26..39 zero) at start of v_sh
  short* xt = (short*)v_sh;
  {
    const short* xflat = (const short*)h0s;
    for (int i = tid; i < 3840; i += 256){
      int row = i/40, col = i - row*40;
      xt[i] = (col < 26) ? xflat[row*26 + col] : (short)0;
    }
  }
  __syncthreads();
  // P2: inproj + bias + LN + relu -> h0s (LDS only)
  for (int m = w; m < 6; m += 4){
    bf8v a = *reinterpret_cast<const bf8v*>(xt + (m*16 + l15)*40 + quad*8);
    f4v acc[8];
    for (int n = 0; n < 8; ++n){
      bf8v bb = *reinterpret_cast<const bf8v*>(Wpp + (n*16 + l15)*32 + quad*8);
      f4v z = {0.f,0.f,0.f,0.f};
      acc[n] = mfma16(a, bb, z);
    }
    float sm[4], sq[4];
    #pragma unroll
    for (int r = 0; r < 4; ++r){ sm[r] = 0.f; sq[r] = 0.f; }
    #pragma unroll
    for (int n = 0; n < 8; ++n){
      int col = n*16 + l15;
      float bv = b2f(bp[col]);
      #pragma unroll
      for (int r = 0; r < 4; ++r){
        float v = acc[n][r] + bv;
        acc[n][r] = v;
        sm[r] += v; sq[r] += v*v;
      }
    }
    #pragma unroll
    for (int mask = 1; mask < 16; mask <<= 1)
      #pragma unroll
      for (int r = 0; r < 4; ++r){
        sm[r] += __shfl_xor(sm[r], mask);
        sq[r] += __shfl_xor(sq[r], mask);
      }
    #pragma unroll
    for (int r = 0; r < 4; ++r){
      float mean = sm[r]*(1.0f/128.0f);
      float var = fmaxf(sq[r]*(1.0f/128.0f) - mean*mean, 0.0f);
      float rs = rsqrtf(var + 1e-5f);
      #pragma unroll
      for (int n = 0; n < 8; ++n){
        int col = n*16 + l15;
        float y = fmaxf((acc[n][r] - mean)*rs*b2f(gp[col]) + b2f(bbp[col]), 0.0f);
        int row = m*16 + quad*4 + r;
        h0s[row*136 + col] = f2bs(y);
      }
    }
  }
  __syncthreads();   // h0s complete; read-only until post-1c barrier

  // vectorized h0 writeback (no barrier needed: h0s read-only here)
  {
    uint4* dst = (uint4*)h0;
    const uint4* srcs = (const uint4*)h0s;
    for (int u = tid; u < 1536; u += 256){
      int r = u >> 4, c = u & 15;
      dst[bn*1536 + u] = srcs[r*17 + c];
    }
  }

  short* vp = v_sh[w];
  short* sw = v_sh[w];       // per-wave scratch; overwritten by V^T after 1b
  const float scl = 0.17677669529663687f;

  bf8v aq[6], bk[6];
  // Phase 1a: Q panels -> registers (Wqkv fragments + bias hoisted)
  {
    bf8v bw[2][4]; float bws[2];
    #pragma unroll
    for (int h = 0; h < 2; ++h){
      int rq = w*32 + h*16 + l15;
      #pragma unroll
      for (int kt = 0; kt < 4; ++kt)
        bw[h][kt] = *reinterpret_cast<const bf8v*>(Wqkv + rq*128 + kt*32 + quad*8);
      bws[h] = b2f(bqkv[rq]);
    }
    for (int m = 0; m < 6; ++m){
      bf8v a[4];
      #pragma unroll
      for (int kt = 0; kt < 4; ++kt)
        a[kt] = *reinterpret_cast<const bf8v*>(h0s + (m*16 + l15)*136 + kt*32 + quad*8);
      #pragma unroll
      for (int h = 0; h < 2; ++h){
        f4v acc = {0.f,0.f,0.f,0.f};
        #pragma unroll
        for (int kt = 0; kt < 4; ++kt) acc = mfma16(a[kt], bw[h][kt], acc);
        #pragma unroll
        for (int r = 0; r < 4; ++r)
          sw[(quad*4 + r)*40 + h*16 + l15] = f2bs((acc[r] + bws[h])*scl);
      }
      asm volatile("s_waitcnt lgkmcnt(0)" ::: "memory");
      aq[m] = *reinterpret_cast<const bf8v*>(sw + l15*40 + quad*8);
    }
  }
  // Phase 1b: K panels -> registers
  {
    bf8v bw[2][4]; float bws[2];
    #pragma unroll
    for (int h = 0; h < 2; ++h){
      int rq = 128 + w*32 + h*16 + l15;
      #pragma unroll
      for (int kt = 0; kt < 4; ++kt)
        bw[h][kt] = *reinterpret_cast<const bf8v*>(Wqkv + rq*128 + kt*32 + quad*8);
      bws[h] = b2f(bqkv[rq]);
    }
    for (int m = 0; m < 6; ++m){
      bf8v a[4];
      #pragma unroll
      for (int kt = 0; kt < 4; ++kt)
        a[kt] = *reinterpret_cast<const bf8v*>(h0s + (m*16 + l15)*136 + kt*32 + quad*8);
      #pragma unroll
      for (int h = 0; h < 2; ++h){
        f4v acc = {0.f,0.f,0.f,0.f};
        #pragma unroll
        for (int kt = 0; kt < 4; ++kt) acc = mfma16(a[kt], bw[h][kt], acc);
        #pragma unroll
        for (int r = 0; r < 4; ++r)
          sw[(quad*4 + r)*40 + h*16 + l15] = f2bs(acc[r] + bws[h]);
      }
      asm volatile("s_waitcnt lgkmcnt(0)" ::: "memory");
      bk[m] = *reinterpret_cast<const bf8v*>(sw + l15*40 + quad*8);
    }
  }
  // Phase 1c: V^T -> LDS (dim x seq)
  {
    bf8v bw[2][4]; float bws[2];
    #pragma unroll
    for (int h = 0; h < 2; ++h){
      int rq = 256 + w*32 + h*16 + l15;
      #pragma unroll
      for (int kt = 0; kt < 4; ++kt)
        bw[h][kt] = *reinterpret_cast<const bf8v*>(Wqkv + rq*128 + kt*32 + quad*8);
      bws[h] = b2f(bqkv[rq]);
    }
    for (int m = 0; m < 6; ++m){
      bf8v a[4];
      #pragma unroll
      for (int kt = 0; kt < 4; ++kt)
        a[kt] = *reinterpret_cast<const bf8v*>(h0s + (m*16 + l15)*136 + kt*32 + quad*8);
      #pragma unroll
      for (int h = 0; h < 2; ++h){
        f4v acc = {0.f,0.f,0.f,0.f};
        #pragma unroll
        for (int kt = 0; kt < 4; ++kt) acc = mfma16(a[kt], bw[h][kt], acc);
        s4v vs;
        #pragma unroll
        for (int r = 0; r < 4; ++r) vs[r] = f2bs(acc[r] + bws[h]);
        *reinterpret_cast<s4v*>(vp + (h*16 + l15)*104 + m*16 + quad*4) = vs;
      }
    }
  }
  __syncthreads();   // h0s -> P panels

  short* pp = h0s + w*1664;   // 16 x 104 bf16 P panel per wave

  for (int m = 0; m < 6; ++m){
    f4v s[6];
    #pragma unroll
    for (int n = 0; n < 6; ++n){
      f4v z = {0.f,0.f,0.f,0.f};
      s[n] = mfma16(aq[m], bk[n], z);
    }
    float mr[4], sr[4];
    #pragma unroll
    for (int r = 0; r < 4; ++r){
      float m0 = fmaxf(fmaxf(s[0][r], s[1][r]), fmaxf(s[2][r], s[3][r]));
      mr[r] = fmaxf(m0, fmaxf(s[4][r], s[5][r]));
    }
    #pragma unroll
    for (int mask = 1; mask < 16; mask <<= 1)
      #pragma unroll
      for (int r = 0; r < 4; ++r) mr[r] = fmaxf(mr[r], __shfl_xor(mr[r], mask));
    #pragma unroll
    for (int r = 0; r < 4; ++r) sr[r] = 0.0f;
    #pragma unroll
    for (int n = 0; n < 6; ++n)
      #pragma unroll
      for (int r = 0; r < 4; ++r){
        float p = __expf(s[n][r] - mr[r]);
        s[n][r] = p;
        sr[r] += p;
      }
    #pragma unroll
    for (int mask = 1; mask < 16; mask <<= 1)
      #pragma unroll
      for (int r = 0; r < 4; ++r) sr[r] += __shfl_xor(sr[r], mask);
    #pragma unroll
    for (int n = 0; n < 6; ++n)
      #pragma unroll
      for (int r = 0; r < 4; ++r)
        pp[(quad*4 + r)*104 + n*16 + l15] = f2bs(s[n][r]);
    asm volatile("s_waitcnt lgkmcnt(0)" ::: "memory");
    f4v o0 = {0.f,0.f,0.f,0.f}, o1 = {0.f,0.f,0.f,0.f};
    #pragma unroll
    for (int ksi = 0; ksi < 3; ++ksi){
      bf8v ap  = *reinterpret_cast<const bf8v*>(pp + l15*104 + ksi*32 + quad*8);
      bf8v bv0 = *reinterpret_cast<const bf8v*>(vp + l15*104 + ksi*32 + quad*8);
      bf8v bv1 = *reinterpret_cast<const bf8v*>(vp + (16 + l15)*104 + ksi*32 + quad*8);
      o0 = mfma16(ap, bv0, o0);
      o1 = mfma16(ap, bv1, o1);
    }
    #pragma unroll
    for (int r = 0; r < 4; ++r){
      float inv = 1.0f/sr[r];
      int row = bn*96 + m*16 + quad*4 + r;
      attno[row*128 + w*32 + l15]      = f2b(o0[r]*inv);
      attno[row*128 + w*32 + 16 + l15] = f2b(o1[r]*inv);
    }
  }
}

// ---------------------------------------------------------------------------
// K3: out-proj + residual + LN. grid = 1200, block = 256.
// VMEM diet: the single 34KB atile is reused 3x -- attno stage -> a-frags,
// h0 stage (uint4) for the residual, then y staging for a uint4 h1 copy-out.
// Replaces 64 scalar global loads + 64 scalar global stores per thread with
// 16 uint4 loads + 8 uint4 stores + cheap LDS traffic.
// ---------------------------------------------------------------------------
__global__ __launch_bounds__(256) void k_oproj(const bf16* __restrict__ attno,
    const bf16* __restrict__ h0, const bf16* __restrict__ Wo,
    const bf16* __restrict__ bo, const bf16* __restrict__ ga,
    const bf16* __restrict__ ba_, bf16* __restrict__ h1){
  int rt = blockIdx.x;
  int tid = threadIdx.x;
  int w = tid >> 6, lane = tid & 63;
  int l15 = lane & 15, quad = lane >> 4;
  __shared__ __align__(16) short atile[128*136];
  // stage attno tile
  {
    const uint4* src = (const uint4*)(attno + rt*16384);
    uint4* dst = (uint4*)atile;
    for (int u = tid; u < 2048; u += 256){
      int r = u >> 4, c = u & 15;
      dst[r*17 + c] = src[u];
    }
  }
  __syncthreads();
  int m0 = w*32;
  bf8v a[2][4];
  #pragma unroll
  for (int m = 0; m < 2; ++m)
    #pragma unroll
    for (int ksi = 0; ksi < 4; ++ksi)
      a[m][ksi] = *reinterpret_cast<const bf8v*>(atile + (m0 + m*16 + l15)*136 + ksi*32 + quad*8);
  __syncthreads();   // all a-frag reads done -> atile reusable
  // stage h0 tile (uint4); GEMM below overlaps the staging loads
  {
    const uint4* src = (const uint4*)(h0 + rt*16384);
    uint4* dst = (uint4*)atile;
    for (int u = tid; u < 2048; u += 256){
      int r = u >> 4, c = u & 15;
      dst[r*17 + c] = src[u];
    }
  }
  f4v acc[2][8];
  #pragma unroll
  for (int m = 0; m < 2; ++m)
    #pragma unroll
    for (int n = 0; n < 8; ++n) acc[m][n] = (f4v){0.f,0.f,0.f,0.f};
  for (int n = 0; n < 8; ++n){
    int G = n*16 + l15;
    bf8v b[4];
    #pragma unroll
    for (int ksi = 0; ksi < 4; ++ksi)
      b[ksi] = *reinterpret_cast<const bf8v*>(Wo + G*128 + ksi*32 + quad*8);
    #pragma unroll
    for (int m = 0; m < 2; ++m)
      #pragma unroll
      for (int ksi = 0; ksi < 4; ++ksi)
        acc[m][n] = mfma16(a[m][ksi], b[ksi], acc[m][n]);
  }
  __syncthreads();   // h0 staged & visible
  #pragma unroll
  for (int m = 0; m < 2; ++m){
    #pragma unroll
    for (int n = 0; n < 8; ++n){
      int col = n*16 + l15;
      float bia = b2f(bo[col]);
      #pragma unroll
      for (int r = 0; r < 4; ++r){
        int lrow = m0 + m*16 + quad*4 + r;
        acc[m][n][r] += bia + s2f(atile[lrow*136 + col]);
      }
    }
    float sm[4], sq[4];
    #pragma unroll
    for (int r = 0; r < 4; ++r){ sm[r] = 0.f; sq[r] = 0.f; }
    #pragma unroll
    for (int n = 0; n < 8; ++n)
      #pragma unroll
      for (int r = 0; r < 4; ++r){
        float v = acc[m][n][r];
        sm[r] += v; sq[r] += v*v;
      }
    #pragma unroll
    for (int mask = 1; mask < 16; mask <<= 1)
      #pragma unroll
      for (int r = 0; r < 4; ++r){
        sm[r] += __shfl_xor(sm[r], mask);
        sq[r] += __shfl_xor(sq[r], mask);
      }
    float mean[4], rs[4];
    #pragma unroll
    for (int r = 0; r < 4; ++r){
      mean[r] = sm[r]*(1.0f/128.0f);
      float var = fmaxf(sq[r]*(1.0f/128.0f) - mean[r]*mean[r], 0.0f);
      rs[r] = rsqrtf(var + 1e-5f);
    }
    // write y back into the SAME thread-private cells (read-before-write per
    // thread; cells are 1:1 thread-owned, so no cross-thread hazard)
    #pragma unroll
    for (int n = 0; n < 8; ++n){
      int col = n*16 + l15;
      float gv = b2f(ga[col]), bv = b2f(ba_[col]);
      #pragma unroll
      for (int r = 0; r < 4; ++r){
        int lrow = m0 + m*16 + quad*4 + r;
        float y = (acc[m][n][r] - mean[r])*rs[r]*gv + bv;
        atile[lrow*136 + col] = f2bs(y);
      }
    }
  }
  __syncthreads();
  // uint4 copy-out to h1
  {
    uint4* dst = (uint4*)(h1 + rt*16384);
    const uint4* src = (const uint4*)atile;
    for (int u = tid; u < 2048; u += 256){
      int r = u >> 4, c = u & 15;
      dst[u] = src[r*17 + c];
    }
  }
}

// ---------------------------------------------------------------------------
// K5: fused forward LSTM + backward single-step + temporal projection.
// grid = 100, block = 512 (8 waves). exp2-prescaled weights + packed gates.
// ---------------------------------------------------------------------------
__global__ __launch_bounds__(512,1) void k_lstm(const bf16* __restrict__ Whh_s,
    const bf16* __restrict__ Wih_s, const float* __restrict__ bias_s,
    const bf16* __restrict__ h1,
    const bf16* __restrict__ Wihb, const bf16* __restrict__ bihb,
    const bf16* __restrict__ bhhb, const bf16* __restrict__ Wtp,
    const bf16* __restrict__ btp, bf16* __restrict__ ht_pad,
    const int* __restrict__ flag, bf16* __restrict__ outb,
    float* __restrict__ outf){
  int bn0 = blockIdx.x * 16;
  int tid = threadIdx.x;
  int w = tid >> 6, lane = tid & 63;
  int l15 = lane & 15, quad = lane >> 4;
  __shared__ __align__(16) short hbuf[2][16*136];
  __shared__ __align__(16) short xbuf[2][16*136];
  __shared__ __align__(16) short ycat[16*264];

  bf8v whh[4][4], wih[4][4];
  float bs[4];
  #pragma unroll
  for (int role = 0; role < 4; ++role){
    int G = role*128 + w*16 + l15;
    #pragma unroll
    for (int kt = 0; kt < 4; ++kt){
      whh[role][kt] = *reinterpret_cast<const bf8v*>(Whh_s + G*128 + kt*32 + quad*8);
      wih[role][kt] = *reinterpret_cast<const bf8v*>(Wih_s + G*128 + kt*32 + quad*8);
    }
    bs[role] = bias_s[G];
  }
  const uint4* h1u4 = (const uint4*)h1;
  int srow = tid >> 4, scol = tid & 15;

  for (int i = tid; i < 16*136; i += 512) hbuf[0][i] = 0;
  if (tid < 256)
    ((uint4*)xbuf[0])[srow*17 + scol] = h1u4[((bn0 + srow)*96 + 0)*16 + scol];
  f4v c0 = {0.f,0.f,0.f,0.f};
  uint4 xpre;
  if (tid < 256) xpre = h1u4[((bn0 + srow)*96 + 1)*16 + scol];
  __syncthreads();

  f4v accx[4];
  {
    bf8v ax[4];
    #pragma unroll
    for (int kt = 0; kt < 4; ++kt)
      ax[kt] = *reinterpret_cast<const bf8v*>(xbuf[0] + l15*136 + kt*32 + quad*8);
    #pragma unroll
    for (int role = 0; role < 4; ++role){
      f4v z = {bs[role], bs[role], bs[role], bs[role]};
      #pragma unroll
      for (int kt = 0; kt < 4; ++kt) z = mfma16(ax[kt], wih[role][kt], z);
      accx[role] = z;
    }
  }
  if (tid < 256) ((uint4*)xbuf[1])[srow*17 + scol] = xpre;
  if (tid < 256) xpre = h1u4[((bn0 + srow)*96 + 2)*16 + scol];
  __syncthreads();

  int colw = w*16 + l15;
  for (int t = 0; t < 96; ++t){
    int cur = t & 1, nxt = cur ^ 1;
    bf8v ah[4], axn[4];
    #pragma unroll
    for (int kt = 0; kt < 4; ++kt){
      ah[kt]  = *reinterpret_cast<const bf8v*>(hbuf[cur] + l15*136 + kt*32 + quad*8);
      axn[kt] = *reinterpret_cast<const bf8v*>(xbuf[nxt] + l15*136 + kt*32 + quad*8);
    }
    f4v acc[4];
    #pragma unroll
    for (int role = 0; role < 4; ++role){
      f4v z = accx[role];
      #pragma unroll
      for (int kt = 0; kt < 4; ++kt) z = mfma16(ah[kt], whh[role][kt], z);
      acc[role] = z;
    }
    #pragma unroll
    for (int role = 0; role < 4; ++role){
      f4v z = {bs[role], bs[role], bs[role], bs[role]};
      #pragma unroll
      for (int kt = 0; kt < 4; ++kt) z = mfma16(axn[kt], wih[role][kt], z);
      accx[role] = z;
    }
    #pragma unroll
    for (int p = 0; p < 2; ++p){
      int r0 = 2*p, r1 = 2*p + 1;
      f2v ai = pk2(acc[0][r0], acc[0][r1]);
      f2v af = pk2(acc[1][r0], acc[1][r1]);
      f2v ag = pk2(acc[2][r0], acc[2][r1]);
      f2v ao = pk2(acc[3][r0], acc[3][r1]);
      f2v ei = pkexp2(pkmin(ai, 40.0f));
      f2v ef = pkexp2(pkmin(af, 40.0f));
      f2v eg = pkexp2(pkmin(pkmax(ag, -40.0f), 40.0f));
      f2v eo = pkexp2(pkmin(ao, 40.0f));
      f2v one = pk2(1.0f, 1.0f);
      f2v Bi = one + ei, Cg = one + eg, Af = one + ef;
      f2v BC = Bi*Cg;
      f2v cs = pk2(c0[r0], c0[r1]);
      f2v cn = cs*BC + (one - eg)*Af;
      f2v c  = cn * pkrcp(Af*BC);
      c0[r0] = c[0]; c0[r1] = c[1];
      f2v cc = pkmin(pkmax(c * -2.88539008178f, -40.0f), 40.0f);
      f2v ec = pkexp2(cc);
      f2v hv = (one - ec) * pkrcp((one + eo)*(one + ec));
      hbuf[nxt][(quad*4 + r0)*136 + colw] = f2bs(hv[0]);
      hbuf[nxt][(quad*4 + r1)*136 + colw] = f2bs(hv[1]);
    }
    if (tid < 256){
      ((uint4*)xbuf[cur])[srow*17 + scol] = xpre;
      int tl = (t + 3 < 96) ? t + 3 : 95;
      xpre = h1u4[((bn0 + srow)*96 + tl)*16 + scol];
    }
    __syncthreads();
  }
  // ---- epilogue: bwd single-step (zero state, x_95 in xbuf[0]) + Wtp ----
  for (int idx = tid; idx < 2048; idx += 512){
    int r = idx >> 7, d = idx & 127;
    ycat[r*264 + d] = hbuf[0][r*136 + d];
  }
  {
    bf8v ax[4];
    #pragma unroll
    for (int kt = 0; kt < 4; ++kt)
      ax[kt] = *reinterpret_cast<const bf8v*>(xbuf[0] + l15*136 + kt*32 + quad*8);
    int col = w*16 + l15;
    f4v gi = {0.f,0.f,0.f,0.f}, gg = {0.f,0.f,0.f,0.f}, go = {0.f,0.f,0.f,0.f};
    #pragma unroll
    for (int kt = 0; kt < 4; ++kt){
      gi = mfma16(ax[kt], *reinterpret_cast<const bf8v*>(Wihb + col*128 + kt*32 + quad*8), gi);
      gg = mfma16(ax[kt], *reinterpret_cast<const bf8v*>(Wihb + (256 + col)*128 + kt*32 + quad*8), gg);
      go = mfma16(ax[kt], *reinterpret_cast<const bf8v*>(Wihb + (384 + col)*128 + kt*32 + quad*8), go);
    }
    float bi = b2f(bihb[col])       + b2f(bhhb[col]);
    float bg = b2f(bihb[256 + col]) + b2f(bhhb[256 + col]);
    float bo = b2f(bihb[384 + col]) + b2f(bhhb[384 + col]);
    #pragma unroll
    for (int r = 0; r < 4; ++r){
      float c  = sigf(gi[r] + bi) * tanhfast(gg[r] + bg);
      float yb = sigf(go[r] + bo) * tanhfast(c);
      ycat[(quad*4 + r)*264 + 128 + col] = f2bs(yb);
    }
  }
  __syncthreads();
  {
    int col = w*16 + l15;
    f4v z = {0.f,0.f,0.f,0.f};
    #pragma unroll
    for (int kt = 0; kt < 8; ++kt){
      bf8v a = *reinterpret_cast<const bf8v*>(ycat + l15*264 + kt*32 + quad*8);
      bf8v bb = *reinterpret_cast<const bf8v*>(Wtp + col*256 + kt*32 + quad*8);
      z = mfma16(a, bb, z);
    }
    float bt = b2f(btp[col]);
    #pragma unroll
    for (int r = 0; r < 4; ++r){
      int rowg = bn0 + quad*4 + r;
      float v = z[r] + bt;
      int bb_ = rowg/100, nn = rowg - bb_*100;
      ht_pad[(bb_*112 + nn)*128 + col] = f2b(v);
      int oi = 206400 + rowg*128 + col;
      if (flag[0]) outb[oi] = f2b(v); else outf[oi] = v;
    }
  }
}

// ---------------------------------------------------------------------------
// K_SPAT: fused spatial pipeline (spat1 + spat2). grid = 16, block = 512.
// ---------------------------------------------------------------------------
__global__ __launch_bounds__(512,1) void k_spat(
    const bf16* __restrict__ ht_pad, const bf16* __restrict__ Hinc,
    const bf16* __restrict__ Wn, const bf16* __restrict__ bn_,
    const bf16* __restrict__ We, const bf16* __restrict__ be,
    const bf16* __restrict__ Wa, const bf16* __restrict__ ba,
    const bf16* __restrict__ gg_, const bf16* __restrict__ bg_,
    bf16* __restrict__ hb2g, const bf16* __restrict__ Anp,
    const bf16* __restrict__ Wg, const bf16* __restrict__ bgc,
    const bf16* __restrict__ Remb, const int* __restrict__ mem,
    const bf16* __restrict__ Wf, const bf16* __restrict__ bf_,
    const bf16* __restrict__ gf, const bf16* __restrict__ b_f,
    const bf16* __restrict__ W1, const bf16* __restrict__ b1,
    const bf16* __restrict__ W2, const bf16* __restrict__ b2,
    const int* __restrict__ flag, bf16* __restrict__ outb,
    float* __restrict__ outf){
  int b = blockIdx.x, tid = threadIdx.x;
  int w = tid >> 6, lane = tid & 63, l15 = lane & 15, quad = lane >> 4;
  __shared__ __align__(16) short htb[112*136];
  __shared__ __align__(16) short mtile[16*136];
  __shared__ float HincS[1600];
  __shared__ float wts[1600];
  __shared__ float eeS[16*128];
  __shared__ float scE[16], degS[16], part[128];
  __shared__ __align__(16) short regA[128*136];
  __shared__ __align__(16) short regB[112*136];

  // ================= phase A: hyperedge attention + node LN =================
  {
    const uint4* src = (const uint4*)(ht_pad + b*14336);
    uint4* dst = (uint4*)htb;
    for (int u = tid; u < 1792; u += 512){
      int r = u >> 4, c = u & 15;
      dst[r*17 + c] = src[u];
    }
  }
  for (int i = tid; i < 1600; i += 512) HincS[i] = b2f(Hinc[i]);
  __syncthreads();
  if (tid < 16){
    float s = 0.0f;
    for (int n = 0; n < 100; ++n) s += HincS[n*16 + tid];
    degS[tid] = s;
  }
  __syncthreads();
  for (int it = 0; it < 4; ++it){
    int idx = tid + it*512;
    int e = idx >> 7, d = idx & 127;
    float s = 0.0f;
    for (int n = 0; n < 100; ++n)
      s += HincS[n*16 + e] * s2f(htb[n*136 + d]);
    mtile[e*136 + d] = f2bs(s * rcpf_(degS[e] + 1e-8f));
  }
  __syncthreads();
  {
    bf8v a[4];
    #pragma unroll
    for (int kt = 0; kt < 4; ++kt)
      a[kt] = *reinterpret_cast<const bf8v*>(mtile + l15*136 + kt*32 + quad*8);
    int col = w*16 + l15;
    f4v z = {0.f,0.f,0.f,0.f};
    #pragma unroll
    for (int kt = 0; kt < 4; ++kt)
      z = mfma16(a[kt], *reinterpret_cast<const bf8v*>(Wn + col*128 + kt*32 + quad*8), z);
    float bnv = b2f(bn_[col]);
    __syncthreads();
    #pragma unroll
    for (int r = 0; r < 4; ++r){
      int e = quad*4 + r;
      float ratio = degS[e] * rcpf_(degS[e] + 1e-8f);
      mtile[e*136 + col] = f2bs(z[r] + bnv*ratio);
    }
  }
  __syncthreads();
  {
    bf8v a[4];
    #pragma unroll
    for (int kt = 0; kt < 4; ++kt)
      a[kt] = *reinterpret_cast<const bf8v*>(mtile + l15*136 + kt*32 + quad*8);
    int col = w*16 + l15;
    f4v z = {0.f,0.f,0.f,0.f};
    #pragma unroll
    for (int kt = 0; kt < 4; ++kt)
      z = mfma16(a[kt], *reinterpret_cast<const bf8v*>(We + col*128 + kt*32 + quad*8), z);
    float bev = b2f(be[col]);
    #pragma unroll
    for (int r = 0; r < 4; ++r)
      eeS[(quad*4 + r)*128 + col] = z[r] + bev;
  }
  __syncthreads();
  if (tid < 128){
    int e = tid >> 3, j = tid & 7;
    float s = 0.0f;
    for (int d = j*16; d < j*16 + 16; ++d)
      s += eeS[e*128 + d] * b2f(Wa[d]);
    part[tid] = s;
  }
  __syncthreads();
  if (tid < 16){
    float s = b2f(ba[0]);
    for (int j = 0; j < 8; ++j) s += part[tid*8 + j];
    scE[tid] = s;
  }
  __syncthreads();
  if (tid < 100){
    float sc[16], mx = -1e30f;
    for (int e = 0; e < 16; ++e){
      sc[e] = (HincS[tid*16 + e] > 0.0f) ? scE[e] : -1e30f;
      mx = fmaxf(mx, sc[e]);
    }
    float sum = 0.0f, tmp[16];
    for (int e = 0; e < 16; ++e){
      tmp[e] = (sc[e] > -1e29f) ? __expf(sc[e] - mx) : 0.0f;
      sum += tmp[e];
    }
    float inv = (sum > 0.0f) ? rcpf_(sum) : 0.0f;
    for (int e = 0; e < 16; ++e) wts[tid*16 + e] = tmp[e]*inv;
  }
  __syncthreads();
  for (int it = 0; it < 13; ++it){
    int n = it*8 + w;
    if (n < 100){
      int d0 = lane*2;
      float s0 = s2f(htb[n*136 + d0]);
      float s1 = s2f(htb[n*136 + d0 + 1]);
      for (int e = 0; e < 16; ++e){
        float wv = wts[n*16 + e];
        s0 += wv * eeS[e*128 + d0];
        s1 += wv * eeS[e*128 + d0 + 1];
      }
      float sum = s0 + s1, sq = s0*s0 + s1*s1;
      #pragma unroll
      for (int mask = 1; mask < 64; mask <<= 1){
        sum += __shfl_xor(sum, mask);
        sq  += __shfl_xor(sq, mask);
      }
      float mean = sum*(1.0f/128.0f);
      float var = fmaxf(sq*(1.0f/128.0f) - mean*mean, 0.0f);
      float rs = rsqrtf(var + 1e-5f);
      float y0 = (s0 - mean)*rs*b2f(gg_[d0])     + b2f(bg_[d0]);
      float y1 = (s1 - mean)*rs*b2f(gg_[d0 + 1]) + b2f(bg_[d0 + 1]);
      hb2g[b*14336 + n*128 + d0]     = f2b(y0);
      hb2g[b*14336 + n*128 + d0 + 1] = f2b(y1);
    }
  }
  __syncthreads();   // hb2g writes drained before phase B reads

  // ================= phase B: GCN + fusion + head =================
  for (int i = tid; i < 128*136; i += 512) regA[i] = 0;
  __syncthreads();
  {
    int c0 = w*16;
    bf8v bw[4];
    #pragma unroll
    for (int kt = 0; kt < 4; ++kt)
      bw[kt] = *reinterpret_cast<const bf8v*>(Wg + (c0 + l15)*128 + kt*32 + quad*8);
    for (int m = 0; m < 7; ++m){
      f4v z = {0.f,0.f,0.f,0.f};
      #pragma unroll
      for (int kt = 0; kt < 4; ++kt){
        bf8v a = *reinterpret_cast<const bf8v*>(hb2g + b*14336 + (m*16 + l15)*128 + kt*32 + quad*8);
        z = mfma16(a, bw[kt], z);
      }
      s4v vs;
      #pragma unroll
      for (int r = 0; r < 4; ++r) vs[r] = f2bs(z[r]);
      *reinterpret_cast<s4v*>(regA + (c0 + l15)*136 + m*16 + quad*4) = vs;
    }
  }
  __syncthreads();
  {
    int c0 = w*16;
    for (int m = 0; m < 7; ++m){
      f4v z = {0.f,0.f,0.f,0.f};
      #pragma unroll
      for (int kt = 0; kt < 4; ++kt){
        bf8v a  = *reinterpret_cast<const bf8v*>(Anp + (m*16 + l15)*128 + kt*32 + quad*8);
        bf8v bb = *reinterpret_cast<const bf8v*>(regA + (c0 + l15)*136 + kt*32 + quad*8);
        z = mfma16(a, bb, z);
      }
      #pragma unroll
      for (int r = 0; r < 4; ++r){
        int row = m*16 + quad*4 + r, col = c0 + l15;
        if (row < 100){
          float v = fmaxf(z[r] + b2f(bgc[col]), 0.0f);
          float o = b2f(hb2g[b*14336 + row*128 + col]) + v
                  + b2f(Remb[mem[row]*128 + col]);
          int oi = 1600 + (b*100 + row)*128 + col;
          if (flag[0]) outb[oi] = f2b(o); else outf[oi] = o;
          regB[row*136 + col] = f2bs(o);
        } else {
          regB[row*136 + col] = 0;
        }
      }
    }
  }
  __syncthreads();
  if (w < 7){
    int m = w;
    f4v acc[8];
    for (int n = 0; n < 8; ++n){
      f4v z = {0.f,0.f,0.f,0.f};
      #pragma unroll
      for (int kt = 0; kt < 4; ++kt){
        bf8v a  = *reinterpret_cast<const bf8v*>(htb + (m*16 + l15)*136 + kt*32 + quad*8);
        bf8v bb = *reinterpret_cast<const bf8v*>(Wf + (n*16 + l15)*256 + kt*32 + quad*8);
        z = mfma16(a, bb, z);
      }
      #pragma unroll
      for (int kt = 0; kt < 4; ++kt){
        bf8v a  = *reinterpret_cast<const bf8v*>(regB + (m*16 + l15)*136 + kt*32 + quad*8);
        bf8v bb = *reinterpret_cast<const bf8v*>(Wf + (n*16 + l15)*256 + 128 + kt*32 + quad*8);
        z = mfma16(a, bb, z);
      }
      acc[n] = z;
    }
    float sm[4], sq[4];
    #pragma unroll
    for (int r = 0; r < 4; ++r){ sm[r] = 0.f; sq[r] = 0.f; }
    #pragma unroll
    for (int n = 0; n < 8; ++n){
      int col = n*16 + l15;
      float bv = b2f(bf_[col]);
      #pragma unroll
      for (int r = 0; r < 4; ++r){
        float v = acc[n][r] + bv;
        acc[n][r] = v;
        sm[r] += v; sq[r] += v*v;
      }
    }
    #pragma unroll
    for (int mask = 1; mask < 16; mask <<= 1)
      #pragma unroll
      for (int r = 0; r < 4; ++r){
        sm[r] += __shfl_xor(sm[r], mask);
        sq[r] += __shfl_xor(sq[r], mask);
      }
    #pragma unroll
    for (int r = 0; r < 4; ++r){
      float mean = sm[r]*(1.0f/128.0f);
      float var = fmaxf(sq[r]*(1.0f/128.0f) - mean*mean, 0.0f);
      float rs = rsqrtf(var + 1e-5f);
      #pragma unroll
      for (int n = 0; n < 8; ++n){
        int col = n*16 + l15;
        float y = fmaxf((acc[n][r] - mean)*rs*b2f(gf[col]) + b2f(b_f[col]), 0.0f);
        regA[(m*16 + quad*4 + r)*136 + col] = f2bs(y);
      }
    }
  }
  __syncthreads();
  if (w < 7){
    int m = w;
    for (int n = 0; n < 4; ++n){
      f4v z = {0.f,0.f,0.f,0.f};
      #pragma unroll
      for (int kt = 0; kt < 4; ++kt){
        bf8v a  = *reinterpret_cast<const bf8v*>(regA + (m*16 + l15)*136 + kt*32 + quad*8);
        bf8v bb = *reinterpret_cast<const bf8v*>(W1 + (n*16 + l15)*128 + kt*32 + quad*8);
        z = mfma16(a, bb, z);
      }
      #pragma unroll
      for (int r = 0; r < 4; ++r){
        int row = m*16 + quad*4 + r, col = n*16 + l15;
        regB[row*72 + col] = f2bs(fmaxf(z[r] + b2f(b1[col]), 0.0f));
      }
    }
  }
  __syncthreads();
  if (tid < 100){
    float s = b2f(b2[0]);
    for (int d = 0; d < 64; ++d)
      s += s2f(regB[tid*72 + d]) * b2f(W2[d]);
    int oi = b*100 + tid;
    if (flag[0]) outb[oi] = f2b(s); else outf[oi] = s;
  }
}

// ---------------------------------------------------------------------------

extern "C" void kernel_launch(void* const* d_in, const int* in_sizes, int n_in,
                              void* d_out, int out_size, void* d_ws, size_t ws_size,
                              hipStream_t stream){
  (void)n_in; (void)out_size; (void)ws_size;
  const int* mem = (const int*)d_in[3];

  CArgs ca;
  int coff[43];
  int nf = 0;
  long long off = 0;
  for (int i = 0; i < 43; ++i){
    if (i == 3){ coff[i] = -1; continue; }
    coff[i] = (int)off;
    ca.src[nf] = d_in[i];
    ca.n[nf]   = in_sizes[i];
    ca.off[nf] = (int)off;
    ++nf;
    off += (long long)((in_sizes[i] + 7) & ~7);
  }
  char* ws = (char*)d_ws;
  bf16* canon = (bf16*)ws;
  long long canonBytes = ((off*2 + 255)/256)*256;
  int* flag = (int*)(ws + canonBytes);
  long long base = canonBytes + 256;

  #define C(i) (canon + coff[i])
  const bf16* A_norm = C(1);
  const bf16* Hinc   = C(2);
  const bf16* Wp  = C(4);  const bf16* bp  = C(5);
  const bf16* g_p = C(6);  const bf16* b_p = C(7);
  const bf16* Wqkv= C(8);  const bf16* bqkv= C(9);
  const bf16* Wo  = C(10); const bf16* bo  = C(11);
  const bf16* g_a = C(12); const bf16* b_a = C(13);
  const bf16* Wih_f = C(14); const bf16* Whh_f = C(15);
  const bf16* bih_f = C(16); const bf16* bhh_f = C(17);
  const bf16* Wih_b = C(18);
  const bf16* bih_b = C(20); const bf16* bhh_b = C(21);
  const bf16* Wtp = C(22); const bf16* btp = C(23);
  const bf16* Wn  = C(24); const bf16* bn_ = C(25);
  const bf16* We  = C(26); const bf16* be  = C(27);
  const bf16* Wa  = C(28); const bf16* ba  = C(29);
  const bf16* g_g = C(30); const bf16* b_g = C(31);
  const bf16* Remb= C(32);
  const bf16* Wg  = C(33); const bf16* bg  = C(34);
  const bf16* Wf  = C(35); const bf16* bff = C(36);
  const bf16* g_f = C(37); const bf16* b_f = C(38);
  const bf16* W1  = C(39); const bf16* b1  = C(40);
  const bf16* W2  = C(41); const bf16* b2  = C(42);
  const bf16* xc  = C(0);
  #undef C

  bf16*  outb = (bf16*)d_out;
  float* outf = (float*)d_out;
  bf16*  h1     = (bf16*)(ws + base);                 // 39,321,600 B
  bf16*  h0     = (bf16*)(ws + base + 39321600LL);    // 39,321,600 B
  bf16*  attno  = (bf16*)(ws + base + 78643200LL);    // 39,321,600 B
  bf16*  Wpp    = (bf16*)(ws + base + 196608000LL);   // 8192 B
  bf16*  An_pad = (bf16*)(ws + base + 196616192LL);   // 28672 B
  bf16*  ht_pad = (bf16*)(ws + base + 196644864LL);   // 458752 B
  bf16*  hb2g   = (bf16*)(ws + base + 197103616LL);   // 458752 B
  bf16*  Whh_s  = (bf16*)(ws + base + 197562368LL);   // 131072 B
  bf16*  Wih_s  = (bf16*)(ws + base + 197693440LL);   // 131072 B
  float* bias_s = (float*)(ws + base + 197824512LL);  // 2048 B

  k_detect<<<1, 256, 0, stream>>>((const unsigned int*)d_in[0], flag);
  k_canon <<<dim3(64, nf), 256, 0, stream>>>(ca, flag, canon);
  k_prep  <<<1024, 256, 0, stream>>>(Wp, A_norm, Whh_f, Wih_f, bih_f, bhh_f,
                                     Wpp, An_pad, ht_pad, hb2g,
                                     Whh_s, Wih_s, bias_s);
  k_inat  <<<1600, 256, 0, stream>>>(xc, Wpp, bp, g_p, b_p, Wqkv, bqkv,
                                     h0, attno);
  k_oproj <<<1200, 256, 0, stream>>>(attno, h0, Wo, bo, g_a, b_a, h1);
  k_lstm  <<<100,  512, 0, stream>>>(Whh_s, Wih_s, bias_s, h1,
                                     Wih_b, bih_b, bhh_b, Wtp, btp, ht_pad,
                                     flag, outb, outf);
  k_spat  <<<16,   512, 0, stream>>>(ht_pad, Hinc, Wn, bn_, We, be, Wa, ba,
                                     g_g, b_g, hb2g, An_pad, Wg, bg, Remb, mem,
                                     Wf, bff, g_f, b_f, W1, b1, W2, b2,
                                     flag, outb, outf);
}

// Round 10
// 436.270 us; speedup vs baseline: 1.0529x; 1.0529x over previous
//
#include <hip/hip_runtime.h>
#include <hip/hip_bf16.h>

typedef __hip_bfloat16 bf16;
typedef __attribute__((ext_vector_type(8))) short bf8v;   // 8 bf16 (4 VGPRs)
typedef __attribute__((ext_vector_type(4))) short s4v;
typedef __attribute__((ext_vector_type(4))) float f4v;
typedef __attribute__((ext_vector_type(2))) float f2v;

#define DEV __device__ __forceinline__

DEV float b2f(bf16 v){ return __bfloat162float(v); }
DEV bf16 f2b(float v){ return __float2bfloat16(v); }
DEV short f2bs(float v){ bf16 t = __float2bfloat16(v); return *reinterpret_cast<short*>(&t); }
DEV float s2f(short s){ return __uint_as_float(((unsigned int)(unsigned short)s) << 16); }
DEV float rcpf_(float x){ return __builtin_amdgcn_rcpf(x); }
DEV float sigf(float x){ return rcpf_(1.0f + __expf(-x)); }
DEV float tanhfast(float x){
  x = fminf(fmaxf(x, -15.0f), 15.0f);
  float e = __expf(-2.0f*x);
  return (1.0f - e)*rcpf_(1.0f + e);
}
// packed helpers (f2v = <2 x float>, LLVM can emit v_pk_* for these)
DEV f2v pk2(float a, float b){ f2v r; r[0]=a; r[1]=b; return r; }
DEV f2v pkmin(f2v a, float b){ return pk2(fminf(a[0],b), fminf(a[1],b)); }
DEV f2v pkmax(f2v a, float b){ return pk2(fmaxf(a[0],b), fmaxf(a[1],b)); }
DEV f2v pkexp2(f2v a){ return pk2(__builtin_amdgcn_exp2f(a[0]), __builtin_amdgcn_exp2f(a[1])); }
DEV f2v pkrcp(f2v a){ return pk2(rcpf_(a[0]), rcpf_(a[1])); }

DEV f4v mfma16(bf8v a, bf8v b, f4v c){
  return __builtin_amdgcn_mfma_f32_16x16x32_bf16(a, b, c, 0, 0, 0);
}

// ---------------------------------------------------------------------------
// K0a: dtype detector (fp32 vs bf16 inputs). flag[0]=1 -> bf16, 0 -> fp32.
// ---------------------------------------------------------------------------
__global__ void k_detect(const unsigned int* __restrict__ xw, int* __restrict__ flag){
  __shared__ int found;
  if (threadIdx.x == 0) found = 0;
  __syncthreads();
  int local = 0;
  for (int i = threadIdx.x; i < 4096; i += 256){
    unsigned int u = xw[i];
    unsigned int e = (u >> 7) & 0xFF;
    if (e >= 0x90) local = 1;
  }
  if (local) atomicOr(&found, 1);
  __syncthreads();
  if (threadIdx.x == 0) flag[0] = found ? 0 : 1;
}

// ---------------------------------------------------------------------------
// K0b: canonicalize all float inputs into a bf16 region in ws.
// Vectorized: 8 elements/iteration (uint4 copy for bf16 path, float4 x2 ->
// 8xbf16 pack for fp32 path), scalar tail. All bases 16B-aligned (offsets
// are 8-element-rounded x 2B; d_in allocations aligned).
// ---------------------------------------------------------------------------
struct CArgs {
  const void* src[44];
  int n[44];
  int off[44];
};

__global__ void k_canon(CArgs a, const int* __restrict__ flag, bf16* __restrict__ dst){
  int id = blockIdx.y;
  int n = a.n[id];
  const void* s = a.src[id];
  bf16* d = dst + a.off[id];
  int nv = n >> 3;
  int stride = gridDim.x * blockDim.x;
  int i0 = blockIdx.x * blockDim.x + threadIdx.x;
  if (flag[0]){
    const uint4* sv = (const uint4*)s;
    uint4* dv = (uint4*)d;
    for (int i = i0; i < nv; i += stride) dv[i] = sv[i];
    const bf16* sb = (const bf16*)s;
    for (int i = (nv << 3) + i0; i < n; i += stride) d[i] = sb[i];
  } else {
    const float4* sv = (const float4*)s;
    s4v* dv = (s4v*)d;
    for (int i = i0; i < nv; i += stride){
      float4 lo = sv[2*i], hi = sv[2*i + 1];
      s4v p0, p1;
      p0[0] = f2bs(lo.x); p0[1] = f2bs(lo.y); p0[2] = f2bs(lo.z); p0[3] = f2bs(lo.w);
      p1[0] = f2bs(hi.x); p1[1] = f2bs(hi.y); p1[2] = f2bs(hi.z); p1[3] = f2bs(hi.w);
      dv[2*i]     = p0;
      dv[2*i + 1] = p1;
    }
    const float* sf = (const float*)s;
    for (int i = (nv << 3) + i0; i < n; i += stride) d[i] = f2b(sf[i]);
  }
}

// ---------------------------------------------------------------------------
// K0c: prep padded operands + exp2-prescaled LSTM weights. Zero-fill of
// ht_pad / hb2_pad vectorized as uint4 (8 bf16 per store).
// Index map: [0,4096) Wpp | [4096,18432) Anp | [18432,83968) Whh_s |
// [83968,149504) Wih_s | [149504,150016) bias_s | [150016,207360) uint4 zeros.
// ---------------------------------------------------------------------------
__global__ void k_prep(const bf16* __restrict__ Wp, const bf16* __restrict__ An,
                       const bf16* __restrict__ Whh, const bf16* __restrict__ Wih,
                       const bf16* __restrict__ bih, const bf16* __restrict__ bhh,
                       bf16* __restrict__ Wpp, bf16* __restrict__ Anp,
                       bf16* __restrict__ htp, bf16* __restrict__ hb2p,
                       bf16* __restrict__ Whh_s, bf16* __restrict__ Wih_s,
                       float* __restrict__ bias_s){
  int stride = gridDim.x * blockDim.x;
  bf16 zero = f2b(0.0f);
  const float L2E = 1.44269504089f;
  for (int i = blockIdx.x*blockDim.x + threadIdx.x; i < 207360; i += stride){
    if (i < 4096){
      int row = i >> 5, col = i & 31;
      Wpp[i] = (col < 26) ? Wp[row*26 + col] : zero;
    } else if (i < 18432){
      int j = i - 4096;
      int row = j >> 7, col = j & 127;
      Anp[j] = (row < 100 && col < 100) ? An[row*100 + col] : zero;
    } else if (i < 83968){
      int j = i - 18432;
      float s = ((j >> 14) == 2) ? -2.0f*L2E : -L2E;
      Whh_s[j] = f2b(b2f(Whh[j]) * s);
    } else if (i < 149504){
      int j = i - 83968;
      float s = ((j >> 14) == 2) ? -2.0f*L2E : -L2E;
      Wih_s[j] = f2b(b2f(Wih[j]) * s);
    } else if (i < 150016){
      int j = i - 149504;
      float s = ((j >> 7) == 2) ? -2.0f*L2E : -L2E;
      bias_s[j] = (b2f(bih[j]) + b2f(bhh[j])) * s;
    } else {
      int j = i - 150016;             // 0..57343 uint4 slots
      uint4 z = {0u,0u,0u,0u};
      if (j < 28672) ((uint4*)htp)[j] = z;
      else           ((uint4*)hb2p)[j - 28672] = z;
    }
  }
}

// ---------------------------------------------------------------------------
// K_INAT (r5 structure + vectorized h0 writeback): fused inproj+LN -> attn.
// grid = 1600, block = 256, LDS 52736 -> 3 blocks/CU. h0 global write is a
// uint4 block-copy from h0s.
// ---------------------------------------------------------------------------
__global__ __launch_bounds__(256,3) void k_inat(const bf16* __restrict__ x,
    const bf16* __restrict__ Wpp, const bf16* __restrict__ bp,
    const bf16* __restrict__ gp, const bf16* __restrict__ bbp,
    const bf16* __restrict__ Wqkv, const bf16* __restrict__ bqkv,
    bf16* __restrict__ h0, bf16* __restrict__ attno){
  int bn = blockIdx.x;
  int tid = threadIdx.x;
  int w = tid >> 6;
  int lane = tid & 63;
  int l15 = lane & 15, quad = lane >> 4;

  __shared__ __align__(16) short h0s[96*136];    // x-flat at P0; P panels later
  __shared__ __align__(16) short v_sh[4][32*104];// xt overlay; sw scratch; V^T

  // P0: stage x flat (96x26 = 312 uint4) into h0s (dead region)
  {
    const uint4* src = (const uint4*)(x + bn*2496);
    uint4* dst = (uint4*)h0s;
    for (int u = tid; u < 312; u += 256) dst[u] = src[u];
  }
  __syncthreads();
  // P1: build xt (96x40, cols 26..39 zero) at start of v_sh
  short* xt = (short*)v_sh;
  {
    const short* xflat = (const short*)h0s;
    for (int i = tid; i < 3840; i += 256){
      int row = i/40, col = i - row*40;
      xt[i] = (col < 26) ? xflat[row*26 + col] : (short)0;
    }
  }
  __syncthreads();
  // P2: inproj + bias + LN + relu -> h0s (LDS only)
  for (int m = w; m < 6; m += 4){
    bf8v a = *reinterpret_cast<const bf8v*>(xt + (m*16 + l15)*40 + quad*8);
    f4v acc[8];
    for (int n = 0; n < 8; ++n){
      bf8v bb = *reinterpret_cast<const bf8v*>(Wpp + (n*16 + l15)*32 + quad*8);
      f4v z = {0.f,0.f,0.f,0.f};
      acc[n] = mfma16(a, bb, z);
    }
    float sm[4], sq[4];
    #pragma unroll
    for (int r = 0; r < 4; ++r){ sm[r] = 0.f; sq[r] = 0.f; }
    #pragma unroll
    for (int n = 0; n < 8; ++n){
      int col = n*16 + l15;
      float bv = b2f(bp[col]);
      #pragma unroll
      for (int r = 0; r < 4; ++r){
        float v = acc[n][r] + bv;
        acc[n][r] = v;
        sm[r] += v; sq[r] += v*v;
      }
    }
    #pragma unroll
    for (int mask = 1; mask < 16; mask <<= 1)
      #pragma unroll
      for (int r = 0; r < 4; ++r){
        sm[r] += __shfl_xor(sm[r], mask);
        sq[r] += __shfl_xor(sq[r], mask);
      }
    #pragma unroll
    for (int r = 0; r < 4; ++r){
      float mean = sm[r]*(1.0f/128.0f);
      float var = fmaxf(sq[r]*(1.0f/128.0f) - mean*mean, 0.0f);
      float rs = rsqrtf(var + 1e-5f);
      #pragma unroll
      for (int n = 0; n < 8; ++n){
        int col = n*16 + l15;
        float y = fmaxf((acc[n][r] - mean)*rs*b2f(gp[col]) + b2f(bbp[col]), 0.0f);
        int row = m*16 + quad*4 + r;
        h0s[row*136 + col] = f2bs(y);
      }
    }
  }
  __syncthreads();   // h0s complete; read-only until post-1c barrier

  // vectorized h0 writeback (h0s read-only here)
  {
    uint4* dst = (uint4*)h0;
    const uint4* srcs = (const uint4*)h0s;
    for (int u = tid; u < 1536; u += 256){
      int r = u >> 4, c = u & 15;
      dst[bn*1536 + u] = srcs[r*17 + c];
    }
  }

  short* vp = v_sh[w];
  short* sw = v_sh[w];       // per-wave scratch; overwritten by V^T after 1b
  const float scl = 0.17677669529663687f;

  bf8v aq[6], bk[6];
  // Phase 1a: Q panels -> registers (Wqkv fragments + bias hoisted)
  {
    bf8v bw[2][4]; float bws[2];
    #pragma unroll
    for (int h = 0; h < 2; ++h){
      int rq = w*32 + h*16 + l15;
      #pragma unroll
      for (int kt = 0; kt < 4; ++kt)
        bw[h][kt] = *reinterpret_cast<const bf8v*>(Wqkv + rq*128 + kt*32 + quad*8);
      bws[h] = b2f(bqkv[rq]);
    }
    for (int m = 0; m < 6; ++m){
      bf8v a[4];
      #pragma unroll
      for (int kt = 0; kt < 4; ++kt)
        a[kt] = *reinterpret_cast<const bf8v*>(h0s + (m*16 + l15)*136 + kt*32 + quad*8);
      #pragma unroll
      for (int h = 0; h < 2; ++h){
        f4v acc = {0.f,0.f,0.f,0.f};
        #pragma unroll
        for (int kt = 0; kt < 4; ++kt) acc = mfma16(a[kt], bw[h][kt], acc);
        #pragma unroll
        for (int r = 0; r < 4; ++r)
          sw[(quad*4 + r)*40 + h*16 + l15] = f2bs((acc[r] + bws[h])*scl);
      }
      asm volatile("s_waitcnt lgkmcnt(0)" ::: "memory");
      aq[m] = *reinterpret_cast<const bf8v*>(sw + l15*40 + quad*8);
    }
  }
  // Phase 1b: K panels -> registers
  {
    bf8v bw[2][4]; float bws[2];
    #pragma unroll
    for (int h = 0; h < 2; ++h){
      int rq = 128 + w*32 + h*16 + l15;
      #pragma unroll
      for (int kt = 0; kt < 4; ++kt)
        bw[h][kt] = *reinterpret_cast<const bf8v*>(Wqkv + rq*128 + kt*32 + quad*8);
      bws[h] = b2f(bqkv[rq]);
    }
    for (int m = 0; m < 6; ++m){
      bf8v a[4];
      #pragma unroll
      for (int kt = 0; kt < 4; ++kt)
        a[kt] = *reinterpret_cast<const bf8v*>(h0s + (m*16 + l15)*136 + kt*32 + quad*8);
      #pragma unroll
      for (int h = 0; h < 2; ++h){
        f4v acc = {0.f,0.f,0.f,0.f};
        #pragma unroll
        for (int kt = 0; kt < 4; ++kt) acc = mfma16(a[kt], bw[h][kt], acc);
        #pragma unroll
        for (int r = 0; r < 4; ++r)
          sw[(quad*4 + r)*40 + h*16 + l15] = f2bs(acc[r] + bws[h]);
      }
      asm volatile("s_waitcnt lgkmcnt(0)" ::: "memory");
      bk[m] = *reinterpret_cast<const bf8v*>(sw + l15*40 + quad*8);
    }
  }
  // Phase 1c: V^T -> LDS (dim x seq)
  {
    bf8v bw[2][4]; float bws[2];
    #pragma unroll
    for (int h = 0; h < 2; ++h){
      int rq = 256 + w*32 + h*16 + l15;
      #pragma unroll
      for (int kt = 0; kt < 4; ++kt)
        bw[h][kt] = *reinterpret_cast<const bf8v*>(Wqkv + rq*128 + kt*32 + quad*8);
      bws[h] = b2f(bqkv[rq]);
    }
    for (int m = 0; m < 6; ++m){
      bf8v a[4];
      #pragma unroll
      for (int kt = 0; kt < 4; ++kt)
        a[kt] = *reinterpret_cast<const bf8v*>(h0s + (m*16 + l15)*136 + kt*32 + quad*8);
      #pragma unroll
      for (int h = 0; h < 2; ++h){
        f4v acc = {0.f,0.f,0.f,0.f};
        #pragma unroll
        for (int kt = 0; kt < 4; ++kt) acc = mfma16(a[kt], bw[h][kt], acc);
        s4v vs;
        #pragma unroll
        for (int r = 0; r < 4; ++r) vs[r] = f2bs(acc[r] + bws[h]);
        *reinterpret_cast<s4v*>(vp + (h*16 + l15)*104 + m*16 + quad*4) = vs;
      }
    }
  }
  __syncthreads();   // h0s -> P panels

  short* pp = h0s + w*1664;   // 16 x 104 bf16 P panel per wave

  for (int m = 0; m < 6; ++m){
    f4v s[6];
    #pragma unroll
    for (int n = 0; n < 6; ++n){
      f4v z = {0.f,0.f,0.f,0.f};
      s[n] = mfma16(aq[m], bk[n], z);
    }
    float mr[4], sr[4];
    #pragma unroll
    for (int r = 0; r < 4; ++r){
      float m0 = fmaxf(fmaxf(s[0][r], s[1][r]), fmaxf(s[2][r], s[3][r]));
      mr[r] = fmaxf(m0, fmaxf(s[4][r], s[5][r]));
    }
    #pragma unroll
    for (int mask = 1; mask < 16; mask <<= 1)
      #pragma unroll
      for (int r = 0; r < 4; ++r) mr[r] = fmaxf(mr[r], __shfl_xor(mr[r], mask));
    #pragma unroll
    for (int r = 0; r < 4; ++r) sr[r] = 0.0f;
    #pragma unroll
    for (int n = 0; n < 6; ++n)
      #pragma unroll
      for (int r = 0; r < 4; ++r){
        float p = __expf(s[n][r] - mr[r]);
        s[n][r] = p;
        sr[r] += p;
      }
    #pragma unroll
    for (int mask = 1; mask < 16; mask <<= 1)
      #pragma unroll
      for (int r = 0; r < 4; ++r) sr[r] += __shfl_xor(sr[r], mask);
    #pragma unroll
    for (int n = 0; n < 6; ++n)
      #pragma unroll
      for (int r = 0; r < 4; ++r)
        pp[(quad*4 + r)*104 + n*16 + l15] = f2bs(s[n][r]);
    asm volatile("s_waitcnt lgkmcnt(0)" ::: "memory");
    f4v o0 = {0.f,0.f,0.f,0.f}, o1 = {0.f,0.f,0.f,0.f};
    #pragma unroll
    for (int ksi = 0; ksi < 3; ++ksi){
      bf8v ap  = *reinterpret_cast<const bf8v*>(pp + l15*104 + ksi*32 + quad*8);
      bf8v bv0 = *reinterpret_cast<const bf8v*>(vp + l15*104 + ksi*32 + quad*8);
      bf8v bv1 = *reinterpret_cast<const bf8v*>(vp + (16 + l15)*104 + ksi*32 + quad*8);
      o0 = mfma16(ap, bv0, o0);
      o1 = mfma16(ap, bv1, o1);
    }
    #pragma unroll
    for (int r = 0; r < 4; ++r){
      float inv = 1.0f/sr[r];
      int row = bn*96 + m*16 + quad*4 + r;
      attno[row*128 + w*32 + l15]      = f2b(o0[r]*inv);
      attno[row*128 + w*32 + 16 + l15] = f2b(o1[r]*inv);
    }
  }
}

// ---------------------------------------------------------------------------
// K3: out-proj + residual + LN. grid = 1200, block = 256.
// atile reused 3x: attno stage -> a-frags, h0 stage (uint4) for residual,
// y staging for a uint4 h1 copy-out.
// ---------------------------------------------------------------------------
__global__ __launch_bounds__(256) void k_oproj(const bf16* __restrict__ attno,
    const bf16* __restrict__ h0, const bf16* __restrict__ Wo,
    const bf16* __restrict__ bo, const bf16* __restrict__ ga,
    const bf16* __restrict__ ba_, bf16* __restrict__ h1){
  int rt = blockIdx.x;
  int tid = threadIdx.x;
  int w = tid >> 6, lane = tid & 63;
  int l15 = lane & 15, quad = lane >> 4;
  __shared__ __align__(16) short atile[128*136];
  {
    const uint4* src = (const uint4*)(attno + rt*16384);
    uint4* dst = (uint4*)atile;
    for (int u = tid; u < 2048; u += 256){
      int r = u >> 4, c = u & 15;
      dst[r*17 + c] = src[u];
    }
  }
  __syncthreads();
  int m0 = w*32;
  bf8v a[2][4];
  #pragma unroll
  for (int m = 0; m < 2; ++m)
    #pragma unroll
    for (int ksi = 0; ksi < 4; ++ksi)
      a[m][ksi] = *reinterpret_cast<const bf8v*>(atile + (m0 + m*16 + l15)*136 + ksi*32 + quad*8);
  __syncthreads();   // all a-frag reads done -> atile reusable
  {
    const uint4* src = (const uint4*)(h0 + rt*16384);
    uint4* dst = (uint4*)atile;
    for (int u = tid; u < 2048; u += 256){
      int r = u >> 4, c = u & 15;
      dst[r*17 + c] = src[u];
    }
  }
  f4v acc[2][8];
  #pragma unroll
  for (int m = 0; m < 2; ++m)
    #pragma unroll
    for (int n = 0; n < 8; ++n) acc[m][n] = (f4v){0.f,0.f,0.f,0.f};
  for (int n = 0; n < 8; ++n){
    int G = n*16 + l15;
    bf8v b[4];
    #pragma unroll
    for (int ksi = 0; ksi < 4; ++ksi)
      b[ksi] = *reinterpret_cast<const bf8v*>(Wo + G*128 + ksi*32 + quad*8);
    #pragma unroll
    for (int m = 0; m < 2; ++m)
      #pragma unroll
      for (int ksi = 0; ksi < 4; ++ksi)
        acc[m][n] = mfma16(a[m][ksi], b[ksi], acc[m][n]);
  }
  __syncthreads();   // h0 staged & visible
  #pragma unroll
  for (int m = 0; m < 2; ++m){
    #pragma unroll
    for (int n = 0; n < 8; ++n){
      int col = n*16 + l15;
      float bia = b2f(bo[col]);
      #pragma unroll
      for (int r = 0; r < 4; ++r){
        int lrow = m0 + m*16 + quad*4 + r;
        acc[m][n][r] += bia + s2f(atile[lrow*136 + col]);
      }
    }
    float sm[4], sq[4];
    #pragma unroll
    for (int r = 0; r < 4; ++r){ sm[r] = 0.f; sq[r] = 0.f; }
    #pragma unroll
    for (int n = 0; n < 8; ++n)
      #pragma unroll
      for (int r = 0; r < 4; ++r){
        float v = acc[m][n][r];
        sm[r] += v; sq[r] += v*v;
      }
    #pragma unroll
    for (int mask = 1; mask < 16; mask <<= 1)
      #pragma unroll
      for (int r = 0; r < 4; ++r){
        sm[r] += __shfl_xor(sm[r], mask);
        sq[r] += __shfl_xor(sq[r], mask);
      }
    float mean[4], rs[4];
    #pragma unroll
    for (int r = 0; r < 4; ++r){
      mean[r] = sm[r]*(1.0f/128.0f);
      float var = fmaxf(sq[r]*(1.0f/128.0f) - mean[r]*mean[r], 0.0f);
      rs[r] = rsqrtf(var + 1e-5f);
    }
    #pragma unroll
    for (int n = 0; n < 8; ++n){
      int col = n*16 + l15;
      float gv = b2f(ga[col]), bv = b2f(ba_[col]);
      #pragma unroll
      for (int r = 0; r < 4; ++r){
        int lrow = m0 + m*16 + quad*4 + r;
        float y = (acc[m][n][r] - mean[r])*rs[r]*gv + bv;
        atile[lrow*136 + col] = f2bs(y);
      }
    }
  }
  __syncthreads();
  {
    uint4* dst = (uint4*)(h1 + rt*16384);
    const uint4* src = (const uint4*)atile;
    for (int u = tid; u < 2048; u += 256){
      int r = u >> 4, c = u & 15;
      dst[u] = src[r*17 + c];
    }
  }
}

// ---------------------------------------------------------------------------
// K5: fused forward LSTM + backward single-step + temporal projection.
// grid = 100, block = 512 (8 waves). exp2-prescaled weights + packed gates.
// ---------------------------------------------------------------------------
__global__ __launch_bounds__(512,1) void k_lstm(const bf16* __restrict__ Whh_s,
    const bf16* __restrict__ Wih_s, const float* __restrict__ bias_s,
    const bf16* __restrict__ h1,
    const bf16* __restrict__ Wihb, const bf16* __restrict__ bihb,
    const bf16* __restrict__ bhhb, const bf16* __restrict__ Wtp,
    const bf16* __restrict__ btp, bf16* __restrict__ ht_pad,
    const int* __restrict__ flag, bf16* __restrict__ outb,
    float* __restrict__ outf){
  int bn0 = blockIdx.x * 16;
  int tid = threadIdx.x;
  int w = tid >> 6, lane = tid & 63;
  int l15 = lane & 15, quad = lane >> 4;
  __shared__ __align__(16) short hbuf[2][16*136];
  __shared__ __align__(16) short xbuf[2][16*136];
  __shared__ __align__(16) short ycat[16*264];

  bf8v whh[4][4], wih[4][4];
  float bs[4];
  #pragma unroll
  for (int role = 0; role < 4; ++role){
    int G = role*128 + w*16 + l15;
    #pragma unroll
    for (int kt = 0; kt < 4; ++kt){
      whh[role][kt] = *reinterpret_cast<const bf8v*>(Whh_s + G*128 + kt*32 + quad*8);
      wih[role][kt] = *reinterpret_cast<const bf8v*>(Wih_s + G*128 + kt*32 + quad*8);
    }
    bs[role] = bias_s[G];
  }
  const uint4* h1u4 = (const uint4*)h1;
  int srow = tid >> 4, scol = tid & 15;

  for (int i = tid; i < 16*136; i += 512) hbuf[0][i] = 0;
  if (tid < 256)
    ((uint4*)xbuf[0])[srow*17 + scol] = h1u4[((bn0 + srow)*96 + 0)*16 + scol];
  f4v c0 = {0.f,0.f,0.f,0.f};
  uint4 xpre;
  if (tid < 256) xpre = h1u4[((bn0 + srow)*96 + 1)*16 + scol];
  __syncthreads();

  f4v accx[4];
  {
    bf8v ax[4];
    #pragma unroll
    for (int kt = 0; kt < 4; ++kt)
      ax[kt] = *reinterpret_cast<const bf8v*>(xbuf[0] + l15*136 + kt*32 + quad*8);
    #pragma unroll
    for (int role = 0; role < 4; ++role){
      f4v z = {bs[role], bs[role], bs[role], bs[role]};
      #pragma unroll
      for (int kt = 0; kt < 4; ++kt) z = mfma16(ax[kt], wih[role][kt], z);
      accx[role] = z;
    }
  }
  if (tid < 256) ((uint4*)xbuf[1])[srow*17 + scol] = xpre;
  if (tid < 256) xpre = h1u4[((bn0 + srow)*96 + 2)*16 + scol];
  __syncthreads();

  int colw = w*16 + l15;
  for (int t = 0; t < 96; ++t){
    int cur = t & 1, nxt = cur ^ 1;
    bf8v ah[4], axn[4];
    #pragma unroll
    for (int kt = 0; kt < 4; ++kt){
      ah[kt]  = *reinterpret_cast<const bf8v*>(hbuf[cur] + l15*136 + kt*32 + quad*8);
      axn[kt] = *reinterpret_cast<const bf8v*>(xbuf[nxt] + l15*136 + kt*32 + quad*8);
    }
    f4v acc[4];
    #pragma unroll
    for (int role = 0; role < 4; ++role){
      f4v z = accx[role];
      #pragma unroll
      for (int kt = 0; kt < 4; ++kt) z = mfma16(ah[kt], whh[role][kt], z);
      acc[role] = z;
    }
    #pragma unroll
    for (int role = 0; role < 4; ++role){
      f4v z = {bs[role], bs[role], bs[role], bs[role]};
      #pragma unroll
      for (int kt = 0; kt < 4; ++kt) z = mfma16(axn[kt], wih[role][kt], z);
      accx[role] = z;
    }
    #pragma unroll
    for (int p = 0; p < 2; ++p){
      int r0 = 2*p, r1 = 2*p + 1;
      f2v ai = pk2(acc[0][r0], acc[0][r1]);
      f2v af = pk2(acc[1][r0], acc[1][r1]);
      f2v ag = pk2(acc[2][r0], acc[2][r1]);
      f2v ao = pk2(acc[3][r0], acc[3][r1]);
      f2v ei = pkexp2(pkmin(ai, 40.0f));
      f2v ef = pkexp2(pkmin(af, 40.0f));
      f2v eg = pkexp2(pkmin(pkmax(ag, -40.0f), 40.0f));
      f2v eo = pkexp2(pkmin(ao, 40.0f));
      f2v one = pk2(1.0f, 1.0f);
      f2v Bi = one + ei, Cg = one + eg, Af = one + ef;
      f2v BC = Bi*Cg;
      f2v cs = pk2(c0[r0], c0[r1]);
      f2v cn = cs*BC + (one - eg)*Af;
      f2v c  = cn * pkrcp(Af*BC);
      c0[r0] = c[0]; c0[r1] = c[1];
      f2v cc = pkmin(pkmax(c * -2.88539008178f, -40.0f), 40.0f);
      f2v ec = pkexp2(cc);
      f2v hv = (one - ec) * pkrcp((one + eo)*(one + ec));
      hbuf[nxt][(quad*4 + r0)*136 + colw] = f2bs(hv[0]);
      hbuf[nxt][(quad*4 + r1)*136 + colw] = f2bs(hv[1]);
    }
    if (tid < 256){
      ((uint4*)xbuf[cur])[srow*17 + scol] = xpre;
      int tl = (t + 3 < 96) ? t + 3 : 95;
      xpre = h1u4[((bn0 + srow)*96 + tl)*16 + scol];
    }
    __syncthreads();
  }
  // ---- epilogue: bwd single-step (zero state, x_95 in xbuf[0]) + Wtp ----
  for (int idx = tid; idx < 2048; idx += 512){
    int r = idx >> 7, d = idx & 127;
    ycat[r*264 + d] = hbuf[0][r*136 + d];
  }
  {
    bf8v ax[4];
    #pragma unroll
    for (int kt = 0; kt < 4; ++kt)
      ax[kt] = *reinterpret_cast<const bf8v*>(xbuf[0] + l15*136 + kt*32 + quad*8);
    int col = w*16 + l15;
    f4v gi = {0.f,0.f,0.f,0.f}, gg = {0.f,0.f,0.f,0.f}, go = {0.f,0.f,0.f,0.f};
    #pragma unroll
    for (int kt = 0; kt < 4; ++kt){
      gi = mfma16(ax[kt], *reinterpret_cast<const bf8v*>(Wihb + col*128 + kt*32 + quad*8), gi);
      gg = mfma16(ax[kt], *reinterpret_cast<const bf8v*>(Wihb + (256 + col)*128 + kt*32 + quad*8), gg);
      go = mfma16(ax[kt], *reinterpret_cast<const bf8v*>(Wihb + (384 + col)*128 + kt*32 + quad*8), go);
    }
    float bi = b2f(bihb[col])       + b2f(bhhb[col]);
    float bg = b2f(bihb[256 + col]) + b2f(bhhb[256 + col]);
    float bo = b2f(bihb[384 + col]) + b2f(bhhb[384 + col]);
    #pragma unroll
    for (int r = 0; r < 4; ++r){
      float c  = sigf(gi[r] + bi) * tanhfast(gg[r] + bg);
      float yb = sigf(go[r] + bo) * tanhfast(c);
      ycat[(quad*4 + r)*264 + 128 + col] = f2bs(yb);
    }
  }
  __syncthreads();
  {
    int col = w*16 + l15;
    f4v z = {0.f,0.f,0.f,0.f};
    #pragma unroll
    for (int kt = 0; kt < 8; ++kt){
      bf8v a = *reinterpret_cast<const bf8v*>(ycat + l15*264 + kt*32 + quad*8);
      bf8v bb = *reinterpret_cast<const bf8v*>(Wtp + col*256 + kt*32 + quad*8);
      z = mfma16(a, bb, z);
    }
    float bt = b2f(btp[col]);
    #pragma unroll
    for (int r = 0; r < 4; ++r){
      int rowg = bn0 + quad*4 + r;
      float v = z[r] + bt;
      int bb_ = rowg/100, nn = rowg - bb_*100;
      ht_pad[(bb_*112 + nn)*128 + col] = f2b(v);
      int oi = 206400 + rowg*128 + col;
      if (flag[0]) outb[oi] = f2b(v); else outf[oi] = v;
    }
  }
}

// ---------------------------------------------------------------------------
// K_SPAT: fused spatial pipeline (spat1 + spat2). grid = 16, block = 512.
// ---------------------------------------------------------------------------
__global__ __launch_bounds__(512,1) void k_spat(
    const bf16* __restrict__ ht_pad, const bf16* __restrict__ Hinc,
    const bf16* __restrict__ Wn, const bf16* __restrict__ bn_,
    const bf16* __restrict__ We, const bf16* __restrict__ be,
    const bf16* __restrict__ Wa, const bf16* __restrict__ ba,
    const bf16* __restrict__ gg_, const bf16* __restrict__ bg_,
    bf16* __restrict__ hb2g, const bf16* __restrict__ Anp,
    const bf16* __restrict__ Wg, const bf16* __restrict__ bgc,
    const bf16* __restrict__ Remb, const int* __restrict__ mem,
    const bf16* __restrict__ Wf, const bf16* __restrict__ bf_,
    const bf16* __restrict__ gf, const bf16* __restrict__ b_f,
    const bf16* __restrict__ W1, const bf16* __restrict__ b1,
    const bf16* __restrict__ W2, const bf16* __restrict__ b2,
    const int* __restrict__ flag, bf16* __restrict__ outb,
    float* __restrict__ outf){
  int b = blockIdx.x, tid = threadIdx.x;
  int w = tid >> 6, lane = tid & 63, l15 = lane & 15, quad = lane >> 4;
  __shared__ __align__(16) short htb[112*136];
  __shared__ __align__(16) short mtile[16*136];
  __shared__ float HincS[1600];
  __shared__ float wts[1600];
  __shared__ float eeS[16*128];
  __shared__ float scE[16], degS[16], part[128];
  __shared__ __align__(16) short regA[128*136];
  __shared__ __align__(16) short regB[112*136];

  // ================= phase A: hyperedge attention + node LN =================
  {
    const uint4* src = (const uint4*)(ht_pad + b*14336);
    uint4* dst = (uint4*)htb;
    for (int u = tid; u < 1792; u += 512){
      int r = u >> 4, c = u & 15;
      dst[r*17 + c] = src[u];
    }
  }
  for (int i = tid; i < 1600; i += 512) HincS[i] = b2f(Hinc[i]);
  __syncthreads();
  if (tid < 16){
    float s = 0.0f;
    for (int n = 0; n < 100; ++n) s += HincS[n*16 + tid];
    degS[tid] = s;
  }
  __syncthreads();
  for (int it = 0; it < 4; ++it){
    int idx = tid + it*512;
    int e = idx >> 7, d = idx & 127;
    float s = 0.0f;
    for (int n = 0; n < 100; ++n)
      s += HincS[n*16 + e] * s2f(htb[n*136 + d]);
    mtile[e*136 + d] = f2bs(s * rcpf_(degS[e] + 1e-8f));
  }
  __syncthreads();
  {
    bf8v a[4];
    #pragma unroll
    for (int kt = 0; kt < 4; ++kt)
      a[kt] = *reinterpret_cast<const bf8v*>(mtile + l15*136 + kt*32 + quad*8);
    int col = w*16 + l15;
    f4v z = {0.f,0.f,0.f,0.f};
    #pragma unroll
    for (int kt = 0; kt < 4; ++kt)
      z = mfma16(a[kt], *reinterpret_cast<const bf8v*>(Wn + col*128 + kt*32 + quad*8), z);
    float bnv = b2f(bn_[col]);
    __syncthreads();
    #pragma unroll
    for (int r = 0; r < 4; ++r){
      int e = quad*4 + r;
      float ratio = degS[e] * rcpf_(degS[e] + 1e-8f);
      mtile[e*136 + col] = f2bs(z[r] + bnv*ratio);
    }
  }
  __syncthreads();
  {
    bf8v a[4];
    #pragma unroll
    for (int kt = 0; kt < 4; ++kt)
      a[kt] = *reinterpret_cast<const bf8v*>(mtile + l15*136 + kt*32 + quad*8);
    int col = w*16 + l15;
    f4v z = {0.f,0.f,0.f,0.f};
    #pragma unroll
    for (int kt = 0; kt < 4; ++kt)
      z = mfma16(a[kt], *reinterpret_cast<const bf8v*>(We + col*128 + kt*32 + quad*8), z);
    float bev = b2f(be[col]);
    #pragma unroll
    for (int r = 0; r < 4; ++r)
      eeS[(quad*4 + r)*128 + col] = z[r] + bev;
  }
  __syncthreads();
  if (tid < 128){
    int e = tid >> 3, j = tid & 7;
    float s = 0.0f;
    for (int d = j*16; d < j*16 + 16; ++d)
      s += eeS[e*128 + d] * b2f(Wa[d]);
    part[tid] = s;
  }
  __syncthreads();
  if (tid < 16){
    float s = b2f(ba[0]);
    for (int j = 0; j < 8; ++j) s += part[tid*8 + j];
    scE[tid] = s;
  }
  __syncthreads();
  if (tid < 100){
    float sc[16], mx = -1e30f;
    for (int e = 0; e < 16; ++e){
      sc[e] = (HincS[tid*16 + e] > 0.0f) ? scE[e] : -1e30f;
      mx = fmaxf(mx, sc[e]);
    }
    float sum = 0.0f, tmp[16];
    for (int e = 0; e < 16; ++e){
      tmp[e] = (sc[e] > -1e29f) ? __expf(sc[e] - mx) : 0.0f;
      sum += tmp[e];
    }
    float inv = (sum > 0.0f) ? rcpf_(sum) : 0.0f;
    for (int e = 0; e < 16; ++e) wts[tid*16 + e] = tmp[e]*inv;
  }
  __syncthreads();
  for (int it = 0; it < 13; ++it){
    int n = it*8 + w;
    if (n < 100){
      int d0 = lane*2;
      float s0 = s2f(htb[n*136 + d0]);
      float s1 = s2f(htb[n*136 + d0 + 1]);
      for (int e = 0; e < 16; ++e){
        float wv = wts[n*16 + e];
        s0 += wv * eeS[e*128 + d0];
        s1 += wv * eeS[e*128 + d0 + 1];
      }
      float sum = s0 + s1, sq = s0*s0 + s1*s1;
      #pragma unroll
      for (int mask = 1; mask < 64; mask <<= 1){
        sum += __shfl_xor(sum, mask);
        sq  += __shfl_xor(sq, mask);
      }
      float mean = sum*(1.0f/128.0f);
      float var = fmaxf(sq*(1.0f/128.0f) - mean*mean, 0.0f);
      float rs = rsqrtf(var + 1e-5f);
      float y0 = (s0 - mean)*rs*b2f(gg_[d0])     + b2f(bg_[d0]);
      float y1 = (s1 - mean)*rs*b2f(gg_[d0 + 1]) + b2f(bg_[d0 + 1]);
      hb2g[b*14336 + n*128 + d0]     = f2b(y0);
      hb2g[b*14336 + n*128 + d0 + 1] = f2b(y1);
    }
  }
  __syncthreads();   // hb2g writes drained before phase B reads

  // ================= phase B: GCN + fusion + head =================
  for (int i = tid; i < 128*136; i += 512) regA[i] = 0;
  __syncthreads();
  {
    int c0 = w*16;
    bf8v bw[4];
    #pragma unroll
    for (int kt = 0; kt < 4; ++kt)
      bw[kt] = *reinterpret_cast<const bf8v*>(Wg + (c0 + l15)*128 + kt*32 + quad*8);
    for (int m = 0; m < 7; ++m){
      f4v z = {0.f,0.f,0.f,0.f};
      #pragma unroll
      for (int kt = 0; kt < 4; ++kt){
        bf8v a = *reinterpret_cast<const bf8v*>(hb2g + b*14336 + (m*16 + l15)*128 + kt*32 + quad*8);
        z = mfma16(a, bw[kt], z);
      }
      s4v vs;
      #pragma unroll
      for (int r = 0; r < 4; ++r) vs[r] = f2bs(z[r]);
      *reinterpret_cast<s4v*>(regA + (c0 + l15)*136 + m*16 + quad*4) = vs;
    }
  }
  __syncthreads();
  {
    int c0 = w*16;
    for (int m = 0; m < 7; ++m){
      f4v z = {0.f,0.f,0.f,0.f};
      #pragma unroll
      for (int kt = 0; kt < 4; ++kt){
        bf8v a  = *reinterpret_cast<const bf8v*>(Anp + (m*16 + l15)*128 + kt*32 + quad*8);
        bf8v bb = *reinterpret_cast<const bf8v*>(regA + (c0 + l15)*136 + kt*32 + quad*8);
        z = mfma16(a, bb, z);
      }
      #pragma unroll
      for (int r = 0; r < 4; ++r){
        int row = m*16 + quad*4 + r, col = c0 + l15;
        if (row < 100){
          float v = fmaxf(z[r] + b2f(bgc[col]), 0.0f);
          float o = b2f(hb2g[b*14336 + row*128 + col]) + v
                  + b2f(Remb[mem[row]*128 + col]);
          int oi = 1600 + (b*100 + row)*128 + col;
          if (flag[0]) outb[oi] = f2b(o); else outf[oi] = o;
          regB[row*136 + col] = f2bs(o);
        } else {
          regB[row*136 + col] = 0;
        }
      }
    }
  }
  __syncthreads();
  if (w < 7){
    int m = w;
    f4v acc[8];
    for (int n = 0; n < 8; ++n){
      f4v z = {0.f,0.f,0.f,0.f};
      #pragma unroll
      for (int kt = 0; kt < 4; ++kt){
        bf8v a  = *reinterpret_cast<const bf8v*>(htb + (m*16 + l15)*136 + kt*32 + quad*8);
        bf8v bb = *reinterpret_cast<const bf8v*>(Wf + (n*16 + l15)*256 + kt*32 + quad*8);
        z = mfma16(a, bb, z);
      }
      #pragma unroll
      for (int kt = 0; kt < 4; ++kt){
        bf8v a  = *reinterpret_cast<const bf8v*>(regB + (m*16 + l15)*136 + kt*32 + quad*8);
        bf8v bb = *reinterpret_cast<const bf8v*>(Wf + (n*16 + l15)*256 + 128 + kt*32 + quad*8);
        z = mfma16(a, bb, z);
      }
      acc[n] = z;
    }
    float sm[4], sq[4];
    #pragma unroll
    for (int r = 0; r < 4; ++r){ sm[r] = 0.f; sq[r] = 0.f; }
    #pragma unroll
    for (int n = 0; n < 8; ++n){
      int col = n*16 + l15;
      float bv = b2f(bf_[col]);
      #pragma unroll
      for (int r = 0; r < 4; ++r){
        float v = acc[n][r] + bv;
        acc[n][r] = v;
        sm[r] += v; sq[r] += v*v;
      }
    }
    #pragma unroll
    for (int mask = 1; mask < 16; mask <<= 1)
      #pragma unroll
      for (int r = 0; r < 4; ++r){
        sm[r] += __shfl_xor(sm[r], mask);
        sq[r] += __shfl_xor(sq[r], mask);
      }
    #pragma unroll
    for (int r = 0; r < 4; ++r){
      float mean = sm[r]*(1.0f/128.0f);
      float var = fmaxf(sq[r]*(1.0f/128.0f) - mean*mean, 0.0f);
      float rs = rsqrtf(var + 1e-5f);
      #pragma unroll
      for (int n = 0; n < 8; ++n){
        int col = n*16 + l15;
        float y = fmaxf((acc[n][r] - mean)*rs*b2f(gf[col]) + b2f(b_f[col]), 0.0f);
        regA[(m*16 + quad*4 + r)*136 + col] = f2bs(y);
      }
    }
  }
  __syncthreads();
  if (w < 7){
    int m = w;
    for (int n = 0; n < 4; ++n){
      f4v z = {0.f,0.f,0.f,0.f};
      #pragma unroll
      for (int kt = 0; kt < 4; ++kt){
        bf8v a  = *reinterpret_cast<const bf8v*>(regA + (m*16 + l15)*136 + kt*32 + quad*8);
        bf8v bb = *reinterpret_cast<const bf8v*>(W1 + (n*16 + l15)*128 + kt*32 + quad*8);
        z = mfma16(a, bb, z);
      }
      #pragma unroll
      for (int r = 0; r < 4; ++r){
        int row = m*16 + quad*4 + r, col = n*16 + l15;
        regB[row*72 + col] = f2bs(fmaxf(z[r] + b2f(b1[col]), 0.0f));
      }
    }
  }
  __syncthreads();
  if (tid < 100){
    float s = b2f(b2[0]);
    for (int d = 0; d < 64; ++d)
      s += s2f(regB[tid*72 + d]) * b2f(W2[d]);
    int oi = b*100 + tid;
    if (flag[0]) outb[oi] = f2b(s); else outf[oi] = s;
  }
}

// ---------------------------------------------------------------------------

extern "C" void kernel_launch(void* const* d_in, const int* in_sizes, int n_in,
                              void* d_out, int out_size, void* d_ws, size_t ws_size,
                              hipStream_t stream){
  (void)n_in; (void)out_size; (void)ws_size;
  const int* mem = (const int*)d_in[3];

  CArgs ca;
  int coff[43];
  int nf = 0;
  long long off = 0;
  for (int i = 0; i < 43; ++i){
    if (i == 3){ coff[i] = -1; continue; }
    coff[i] = (int)off;
    ca.src[nf] = d_in[i];
    ca.n[nf]   = in_sizes[i];
    ca.off[nf] = (int)off;
    ++nf;
    off += (long long)((in_sizes[i] + 7) & ~7);
  }
  char* ws = (char*)d_ws;
  bf16* canon = (bf16*)ws;
  long long canonBytes = ((off*2 + 255)/256)*256;
  int* flag = (int*)(ws + canonBytes);
  long long base = canonBytes + 256;

  #define C(i) (canon + coff[i])
  const bf16* A_norm = C(1);
  const bf16* Hinc   = C(2);
  const bf16* Wp  = C(4);  const bf16* bp  = C(5);
  const bf16* g_p = C(6);  const bf16* b_p = C(7);
  const bf16* Wqkv= C(8);  const bf16* bqkv= C(9);
  const bf16* Wo  = C(10); const bf16* bo  = C(11);
  const bf16* g_a = C(12); const bf16* b_a = C(13);
  const bf16* Wih_f = C(14); const bf16* Whh_f = C(15);
  const bf16* bih_f = C(16); const bf16* bhh_f = C(17);
  const bf16* Wih_b = C(18);
  const bf16* bih_b = C(20); const bf16* bhh_b = C(21);
  const bf16* Wtp = C(22); const bf16* btp = C(23);
  const bf16* Wn  = C(24); const bf16* bn_ = C(25);
  const bf16* We  = C(26); const bf16* be  = C(27);
  const bf16* Wa  = C(28); const bf16* ba  = C(29);
  const bf16* g_g = C(30); const bf16* b_g = C(31);
  const bf16* Remb= C(32);
  const bf16* Wg  = C(33); const bf16* bg  = C(34);
  const bf16* Wf  = C(35); const bf16* bff = C(36);
  const bf16* g_f = C(37); const bf16* b_f = C(38);
  const bf16* W1  = C(39); const bf16* b1  = C(40);
  const bf16* W2  = C(41); const bf16* b2  = C(42);
  const bf16* xc  = C(0);
  #undef C

  bf16*  outb = (bf16*)d_out;
  float* outf = (float*)d_out;
  bf16*  h1     = (bf16*)(ws + base);                 // 39,321,600 B
  bf16*  h0     = (bf16*)(ws + base + 39321600LL);    // 39,321,600 B
  bf16*  attno  = (bf16*)(ws + base + 78643200LL);    // 39,321,600 B
  bf16*  Wpp    = (bf16*)(ws + base + 196608000LL);   // 8192 B
  bf16*  An_pad = (bf16*)(ws + base + 196616192LL);   // 28672 B
  bf16*  ht_pad = (bf16*)(ws + base + 196644864LL);   // 458752 B
  bf16*  hb2g   = (bf16*)(ws + base + 197103616LL);   // 458752 B
  bf16*  Whh_s  = (bf16*)(ws + base + 197562368LL);   // 131072 B
  bf16*  Wih_s  = (bf16*)(ws + base + 197693440LL);   // 131072 B
  float* bias_s = (float*)(ws + base + 197824512LL);  // 2048 B

  k_detect<<<1, 256, 0, stream>>>((const unsigned int*)d_in[0], flag);
  k_canon <<<dim3(64, nf), 256, 0, stream>>>(ca, flag, canon);
  k_prep  <<<512, 256, 0, stream>>>(Wp, A_norm, Whh_f, Wih_f, bih_f, bhh_f,
                                    Wpp, An_pad, ht_pad, hb2g,
                                    Whh_s, Wih_s, bias_s);
  k_inat  <<<1600, 256, 0, stream>>>(xc, Wpp, bp, g_p, b_p, Wqkv, bqkv,
                                     h0, attno);
  k_oproj <<<1200, 256, 0, stream>>>(attno, h0, Wo, bo, g_a, b_a, h1);
  k_lstm  <<<100,  512, 0, stream>>>(Whh_s, Wih_s, bias_s, h1,
                                     Wih_b, bih_b, bhh_b, Wtp, btp, ht_pad,
                                     flag, outb, outf);
  k_spat  <<<16,   512, 0, stream>>>(ht_pad, Hinc, Wn, bn_, We, be, Wa, ba,
                                     g_g, b_g, hb2g, An_pad, Wg, bg, Remb, mem,
                                     Wf, bff, g_f, b_f, W1, b1, W2, b2,
                                     flag, outb, outf);
}

// Round 11
// 428.161 us; speedup vs baseline: 1.0728x; 1.0189x over previous
//
#include <hip/hip_runtime.h>
#include <hip/hip_bf16.h>

typedef __hip_bfloat16 bf16;
typedef __attribute__((ext_vector_type(8))) short bf8v;   // 8 bf16 (4 VGPRs)
typedef __attribute__((ext_vector_type(4))) short s4v;
typedef __attribute__((ext_vector_type(4))) float f4v;
typedef __attribute__((ext_vector_type(2))) float f2v;

#define DEV __device__ __forceinline__

DEV float b2f(bf16 v){ return __bfloat162float(v); }
DEV bf16 f2b(float v){ return __float2bfloat16(v); }
DEV short f2bs(float v){ bf16 t = __float2bfloat16(v); return *reinterpret_cast<short*>(&t); }
DEV float s2f(short s){ return __uint_as_float(((unsigned int)(unsigned short)s) << 16); }
DEV float rcpf_(float x){ return __builtin_amdgcn_rcpf(x); }
DEV float sigf(float x){ return rcpf_(1.0f + __expf(-x)); }
DEV float tanhfast(float x){
  x = fminf(fmaxf(x, -15.0f), 15.0f);
  float e = __expf(-2.0f*x);
  return (1.0f - e)*rcpf_(1.0f + e);
}
// packed helpers (f2v = <2 x float>, LLVM can emit v_pk_* for these)
DEV f2v pk2(float a, float b){ f2v r; r[0]=a; r[1]=b; return r; }
DEV f2v pkmin(f2v a, float b){ return pk2(fminf(a[0],b), fminf(a[1],b)); }
DEV f2v pkmax(f2v a, float b){ return pk2(fmaxf(a[0],b), fmaxf(a[1],b)); }
DEV f2v pkexp2(f2v a){ return pk2(__builtin_amdgcn_exp2f(a[0]), __builtin_amdgcn_exp2f(a[1])); }
DEV f2v pkrcp(f2v a){ return pk2(rcpf_(a[0]), rcpf_(a[1])); }

DEV f4v mfma16(bf8v a, bf8v b, f4v c){
  return __builtin_amdgcn_mfma_f32_16x16x32_bf16(a, b, c, 0, 0, 0);
}

// ---------------------------------------------------------------------------
// K_PRE: merged detect + canon + prep. grid = (64, nf+1), block = 256.
// Each block derives the dtype flag locally from 512 raw x words (safe:
// fp32 mantissa bits trigger >=0x90 with p~0.44/word; bf16 N(0,1) exponents
// never reach 0x90). y<nf: canonicalize array y. y==nf: padded operands +
// exp2-prescaled LSTM weights from RAW inputs with canon-matching rounding.
// ---------------------------------------------------------------------------
struct CArgs {
  const void* src[44];
  int n[44];
  int off[44];
};

DEV float ldrb(const void* p, int i, int isb){
  float v = isb ? b2f(((const bf16*)p)[i]) : ((const float*)p)[i];
  return b2f(f2b(v));     // match canon's bf16 rounding exactly
}

__global__ void k_pre(CArgs a, int nf, const unsigned int* __restrict__ xw,
                      const void* rWp, const void* rAn, const void* rWhh,
                      const void* rWih, const void* rbih, const void* rbhh,
                      bf16* __restrict__ dst, int* __restrict__ flag,
                      bf16* __restrict__ Wpp, bf16* __restrict__ Anp,
                      bf16* __restrict__ htp, bf16* __restrict__ hb2p,
                      bf16* __restrict__ Whh_s, bf16* __restrict__ Wih_s,
                      float* __restrict__ bias_s){
  __shared__ int found;
  if (threadIdx.x == 0) found = 0;
  __syncthreads();
  {
    int local = 0;
    for (int i = threadIdx.x; i < 512; i += 256){
      unsigned int e = (xw[i] >> 7) & 0xFF;
      if (e >= 0x90) local = 1;
    }
    if (local) atomicOr(&found, 1);
  }
  __syncthreads();
  int isb = found ? 0 : 1;
  int id = blockIdx.y;

  if (id < nf){
    // ---- canon slice (vectorized; 8 elems/iter) ----
    int n = a.n[id];
    const void* s = a.src[id];
    bf16* d = dst + a.off[id];
    int nv = n >> 3;
    int stride = gridDim.x * blockDim.x;
    int i0 = blockIdx.x * blockDim.x + threadIdx.x;
    if (isb){
      const uint4* sv = (const uint4*)s;
      uint4* dv = (uint4*)d;
      for (int i = i0; i < nv; i += stride) dv[i] = sv[i];
      const bf16* sb = (const bf16*)s;
      for (int i = (nv << 3) + i0; i < n; i += stride) d[i] = sb[i];
    } else {
      const float4* sv = (const float4*)s;
      s4v* dv = (s4v*)d;
      for (int i = i0; i < nv; i += stride){
        float4 lo = sv[2*i], hi = sv[2*i + 1];
        s4v p0, p1;
        p0[0] = f2bs(lo.x); p0[1] = f2bs(lo.y); p0[2] = f2bs(lo.z); p0[3] = f2bs(lo.w);
        p1[0] = f2bs(hi.x); p1[1] = f2bs(hi.y); p1[2] = f2bs(hi.z); p1[3] = f2bs(hi.w);
        dv[2*i]     = p0;
        dv[2*i + 1] = p1;
      }
      const float* sf = (const float*)s;
      for (int i = (nv << 3) + i0; i < n; i += stride) d[i] = f2b(sf[i]);
    }
  } else {
    // ---- prep slice (raw inputs; overlapped with canon) ----
    if (blockIdx.x == 0 && threadIdx.x == 0) flag[0] = isb;
    int stride = gridDim.x * blockDim.x;
    bf16 zero = f2b(0.0f);
    const float L2E = 1.44269504089f;
    for (int i = blockIdx.x*blockDim.x + threadIdx.x; i < 207360; i += stride){
      if (i < 4096){
        int row = i >> 5, col = i & 31;
        Wpp[i] = (col < 26) ? f2b(ldrb(rWp, row*26 + col, isb)) : zero;
      } else if (i < 18432){
        int j = i - 4096;
        int row = j >> 7, col = j & 127;
        Anp[j] = (row < 100 && col < 100) ? f2b(ldrb(rAn, row*100 + col, isb)) : zero;
      } else if (i < 83968){
        int j = i - 18432;
        float s = ((j >> 14) == 2) ? -2.0f*L2E : -L2E;
        Whh_s[j] = f2b(ldrb(rWhh, j, isb) * s);
      } else if (i < 149504){
        int j = i - 83968;
        float s = ((j >> 14) == 2) ? -2.0f*L2E : -L2E;
        Wih_s[j] = f2b(ldrb(rWih, j, isb) * s);
      } else if (i < 150016){
        int j = i - 149504;
        float s = ((j >> 7) == 2) ? -2.0f*L2E : -L2E;
        bias_s[j] = (ldrb(rbih, j, isb) + ldrb(rbhh, j, isb)) * s;
      } else {
        int j = i - 150016;             // 0..57343 uint4 slots
        uint4 z = {0u,0u,0u,0u};
        if (j < 28672) ((uint4*)htp)[j] = z;
        else           ((uint4*)hb2p)[j - 28672] = z;
      }
    }
  }
}

// ---------------------------------------------------------------------------
// K_INAT: fused inproj+LN -> attention. grid = 1600, block = 256.
// LDS 52736 -> 3 blocks/CU; hoisted Wqkv frags; uint4 h0 writeback;
// exp2-domain softmax (log2e folded into Q scale); attno written via pp
// staging + one global_store_dwordx4 per thread per m.
// ---------------------------------------------------------------------------
__global__ __launch_bounds__(256,3) void k_inat(const bf16* __restrict__ x,
    const bf16* __restrict__ Wpp, const bf16* __restrict__ bp,
    const bf16* __restrict__ gp, const bf16* __restrict__ bbp,
    const bf16* __restrict__ Wqkv, const bf16* __restrict__ bqkv,
    bf16* __restrict__ h0, bf16* __restrict__ attno){
  int bn = blockIdx.x;
  int tid = threadIdx.x;
  int w = tid >> 6;
  int lane = tid & 63;
  int l15 = lane & 15, quad = lane >> 4;

  __shared__ __align__(16) short h0s[96*136];    // x-flat at P0; P panels later
  __shared__ __align__(16) short v_sh[4][32*104];// xt overlay; sw scratch; V^T

  // P0: stage x flat (96x26 = 312 uint4) into h0s (dead region)
  {
    const uint4* src = (const uint4*)(x + bn*2496);
    uint4* dst = (uint4*)h0s;
    for (int u = tid; u < 312; u += 256) dst[u] = src[u];
  }
  __syncthreads();
  // P1: build xt (96x40, cols 26..39 zero) at start of v_sh
  short* xt = (short*)v_sh;
  {
    const short* xflat = (const short*)h0s;
    for (int i = tid; i < 3840; i += 256){
      int row = i/40, col = i - row*40;
      xt[i] = (col < 26) ? xflat[row*26 + col] : (short)0;
    }
  }
  __syncthreads();
  // P2: inproj + bias + LN + relu -> h0s (LDS only)
  for (int m = w; m < 6; m += 4){
    bf8v a = *reinterpret_cast<const bf8v*>(xt + (m*16 + l15)*40 + quad*8);
    f4v acc[8];
    for (int n = 0; n < 8; ++n){
      bf8v bb = *reinterpret_cast<const bf8v*>(Wpp + (n*16 + l15)*32 + quad*8);
      f4v z = {0.f,0.f,0.f,0.f};
      acc[n] = mfma16(a, bb, z);
    }
    float sm[4], sq[4];
    #pragma unroll
    for (int r = 0; r < 4; ++r){ sm[r] = 0.f; sq[r] = 0.f; }
    #pragma unroll
    for (int n = 0; n < 8; ++n){
      int col = n*16 + l15;
      float bv = b2f(bp[col]);
      #pragma unroll
      for (int r = 0; r < 4; ++r){
        float v = acc[n][r] + bv;
        acc[n][r] = v;
        sm[r] += v; sq[r] += v*v;
      }
    }
    #pragma unroll
    for (int mask = 1; mask < 16; mask <<= 1)
      #pragma unroll
      for (int r = 0; r < 4; ++r){
        sm[r] += __shfl_xor(sm[r], mask);
        sq[r] += __shfl_xor(sq[r], mask);
      }
    #pragma unroll
    for (int r = 0; r < 4; ++r){
      float mean = sm[r]*(1.0f/128.0f);
      float var = fmaxf(sq[r]*(1.0f/128.0f) - mean*mean, 0.0f);
      float rs = rsqrtf(var + 1e-5f);
      #pragma unroll
      for (int n = 0; n < 8; ++n){
        int col = n*16 + l15;
        float y = fmaxf((acc[n][r] - mean)*rs*b2f(gp[col]) + b2f(bbp[col]), 0.0f);
        int row = m*16 + quad*4 + r;
        h0s[row*136 + col] = f2bs(y);
      }
    }
  }
  __syncthreads();   // h0s complete; read-only until post-1c barrier

  // vectorized h0 writeback (h0s read-only here)
  {
    uint4* dst = (uint4*)h0;
    const uint4* srcs = (const uint4*)h0s;
    for (int u = tid; u < 1536; u += 256){
      int r = u >> 4, c = u & 15;
      dst[bn*1536 + u] = srcs[r*17 + c];
    }
  }

  short* vp = v_sh[w];
  short* sw = v_sh[w];       // per-wave scratch; overwritten by V^T after 1b
  // scl = log2e / sqrt(32): scores land in log2 domain -> exp2 softmax
  const float scl = 0.2550348347f;

  bf8v aq[6], bk[6];
  // Phase 1a: Q panels -> registers (Wqkv fragments + bias hoisted)
  {
    bf8v bw[2][4]; float bws[2];
    #pragma unroll
    for (int h = 0; h < 2; ++h){
      int rq = w*32 + h*16 + l15;
      #pragma unroll
      for (int kt = 0; kt < 4; ++kt)
        bw[h][kt] = *reinterpret_cast<const bf8v*>(Wqkv + rq*128 + kt*32 + quad*8);
      bws[h] = b2f(bqkv[rq]);
    }
    for (int m = 0; m < 6; ++m){
      bf8v a[4];
      #pragma unroll
      for (int kt = 0; kt < 4; ++kt)
        a[kt] = *reinterpret_cast<const bf8v*>(h0s + (m*16 + l15)*136 + kt*32 + quad*8);
      #pragma unroll
      for (int h = 0; h < 2; ++h){
        f4v acc = {0.f,0.f,0.f,0.f};
        #pragma unroll
        for (int kt = 0; kt < 4; ++kt) acc = mfma16(a[kt], bw[h][kt], acc);
        #pragma unroll
        for (int r = 0; r < 4; ++r)
          sw[(quad*4 + r)*40 + h*16 + l15] = f2bs((acc[r] + bws[h])*scl);
      }
      asm volatile("s_waitcnt lgkmcnt(0)" ::: "memory");
      aq[m] = *reinterpret_cast<const bf8v*>(sw + l15*40 + quad*8);
    }
  }
  // Phase 1b: K panels -> registers
  {
    bf8v bw[2][4]; float bws[2];
    #pragma unroll
    for (int h = 0; h < 2; ++h){
      int rq = 128 + w*32 + h*16 + l15;
      #pragma unroll
      for (int kt = 0; kt < 4; ++kt)
        bw[h][kt] = *reinterpret_cast<const bf8v*>(Wqkv + rq*128 + kt*32 + quad*8);
      bws[h] = b2f(bqkv[rq]);
    }
    for (int m = 0; m < 6; ++m){
      bf8v a[4];
      #pragma unroll
      for (int kt = 0; kt < 4; ++kt)
        a[kt] = *reinterpret_cast<const bf8v*>(h0s + (m*16 + l15)*136 + kt*32 + quad*8);
      #pragma unroll
      for (int h = 0; h < 2; ++h){
        f4v acc = {0.f,0.f,0.f,0.f};
        #pragma unroll
        for (int kt = 0; kt < 4; ++kt) acc = mfma16(a[kt], bw[h][kt], acc);
        #pragma unroll
        for (int r = 0; r < 4; ++r)
          sw[(quad*4 + r)*40 + h*16 + l15] = f2bs(acc[r] + bws[h]);
      }
      asm volatile("s_waitcnt lgkmcnt(0)" ::: "memory");
      bk[m] = *reinterpret_cast<const bf8v*>(sw + l15*40 + quad*8);
    }
  }
  // Phase 1c: V^T -> LDS (dim x seq)
  {
    bf8v bw[2][4]; float bws[2];
    #pragma unroll
    for (int h = 0; h < 2; ++h){
      int rq = 256 + w*32 + h*16 + l15;
      #pragma unroll
      for (int kt = 0; kt < 4; ++kt)
        bw[h][kt] = *reinterpret_cast<const bf8v*>(Wqkv + rq*128 + kt*32 + quad*8);
      bws[h] = b2f(bqkv[rq]);
    }
    for (int m = 0; m < 6; ++m){
      bf8v a[4];
      #pragma unroll
      for (int kt = 0; kt < 4; ++kt)
        a[kt] = *reinterpret_cast<const bf8v*>(h0s + (m*16 + l15)*136 + kt*32 + quad*8);
      #pragma unroll
      for (int h = 0; h < 2; ++h){
        f4v acc = {0.f,0.f,0.f,0.f};
        #pragma unroll
        for (int kt = 0; kt < 4; ++kt) acc = mfma16(a[kt], bw[h][kt], acc);
        s4v vs;
        #pragma unroll
        for (int r = 0; r < 4; ++r) vs[r] = f2bs(acc[r] + bws[h]);
        *reinterpret_cast<s4v*>(vp + (h*16 + l15)*104 + m*16 + quad*4) = vs;
      }
    }
  }
  __syncthreads();   // h0s -> P panels

  short* pp = h0s + w*1664;   // 16 x 104 bf16 P panel per wave
  int orow = lane >> 2, oc4 = lane & 3;   // output copy mapping

  for (int m = 0; m < 6; ++m){
    f4v s[6];
    #pragma unroll
    for (int n = 0; n < 6; ++n){
      f4v z = {0.f,0.f,0.f,0.f};
      s[n] = mfma16(aq[m], bk[n], z);
    }
    float mr[4], sr[4];
    #pragma unroll
    for (int r = 0; r < 4; ++r){
      float m0 = fmaxf(fmaxf(s[0][r], s[1][r]), fmaxf(s[2][r], s[3][r]));
      mr[r] = fmaxf(m0, fmaxf(s[4][r], s[5][r]));
    }
    #pragma unroll
    for (int mask = 1; mask < 16; mask <<= 1)
      #pragma unroll
      for (int r = 0; r < 4; ++r) mr[r] = fmaxf(mr[r], __shfl_xor(mr[r], mask));
    #pragma unroll
    for (int r = 0; r < 4; ++r) sr[r] = 0.0f;
    #pragma unroll
    for (int n = 0; n < 6; ++n)
      #pragma unroll
      for (int r = 0; r < 4; ++r){
        float p = __builtin_amdgcn_exp2f(s[n][r] - mr[r]);   // scores in log2 dom
        s[n][r] = p;
        sr[r] += p;
      }
    #pragma unroll
    for (int mask = 1; mask < 16; mask <<= 1)
      #pragma unroll
      for (int r = 0; r < 4; ++r) sr[r] += __shfl_xor(sr[r], mask);
    #pragma unroll
    for (int n = 0; n < 6; ++n)
      #pragma unroll
      for (int r = 0; r < 4; ++r)
        pp[(quad*4 + r)*104 + n*16 + l15] = f2bs(s[n][r]);
    asm volatile("s_waitcnt lgkmcnt(0)" ::: "memory");
    f4v o0 = {0.f,0.f,0.f,0.f}, o1 = {0.f,0.f,0.f,0.f};
    #pragma unroll
    for (int ksi = 0; ksi < 3; ++ksi){
      bf8v ap  = *reinterpret_cast<const bf8v*>(pp + l15*104 + ksi*32 + quad*8);
      bf8v bv0 = *reinterpret_cast<const bf8v*>(vp + l15*104 + ksi*32 + quad*8);
      bf8v bv1 = *reinterpret_cast<const bf8v*>(vp + (16 + l15)*104 + ksi*32 + quad*8);
      o0 = mfma16(ap, bv0, o0);
      o1 = mfma16(ap, bv1, o1);
    }
    // stage output block (16 rows x 32 cols) into pp head (in-wave DS order:
    // PV reads above precede these writes), then one uint4 store per thread.
    #pragma unroll
    for (int r = 0; r < 4; ++r){
      float inv = 1.0f/sr[r];
      pp[(quad*4 + r)*32 + l15]      = f2bs(o0[r]*inv);
      pp[(quad*4 + r)*32 + 16 + l15] = f2bs(o1[r]*inv);
    }
    asm volatile("s_waitcnt lgkmcnt(0)" ::: "memory");
    {
      uint4 v = ((const uint4*)pp)[orow*4 + oc4];
      *reinterpret_cast<uint4*>(attno + (bn*96 + m*16 + orow)*128 + w*32 + oc4*8) = v;
    }
  }
}

// ---------------------------------------------------------------------------
// K3: out-proj + residual + LN. grid = 1200, block = 256.
// atile reused 3x: attno stage -> a-frags, h0 stage (uint4) for residual,
// y staging for a uint4 h1 copy-out.
// ---------------------------------------------------------------------------
__global__ __launch_bounds__(256) void k_oproj(const bf16* __restrict__ attno,
    const bf16* __restrict__ h0, const bf16* __restrict__ Wo,
    const bf16* __restrict__ bo, const bf16* __restrict__ ga,
    const bf16* __restrict__ ba_, bf16* __restrict__ h1){
  int rt = blockIdx.x;
  int tid = threadIdx.x;
  int w = tid >> 6, lane = tid & 63;
  int l15 = lane & 15, quad = lane >> 4;
  __shared__ __align__(16) short atile[128*136];
  {
    const uint4* src = (const uint4*)(attno + rt*16384);
    uint4* dst = (uint4*)atile;
    for (int u = tid; u < 2048; u += 256){
      int r = u >> 4, c = u & 15;
      dst[r*17 + c] = src[u];
    }
  }
  __syncthreads();
  int m0 = w*32;
  bf8v a[2][4];
  #pragma unroll
  for (int m = 0; m < 2; ++m)
    #pragma unroll
    for (int ksi = 0; ksi < 4; ++ksi)
      a[m][ksi] = *reinterpret_cast<const bf8v*>(atile + (m0 + m*16 + l15)*136 + ksi*32 + quad*8);
  __syncthreads();   // all a-frag reads done -> atile reusable
  {
    const uint4* src = (const uint4*)(h0 + rt*16384);
    uint4* dst = (uint4*)atile;
    for (int u = tid; u < 2048; u += 256){
      int r = u >> 4, c = u & 15;
      dst[r*17 + c] = src[u];
    }
  }
  f4v acc[2][8];
  #pragma unroll
  for (int m = 0; m < 2; ++m)
    #pragma unroll
    for (int n = 0; n < 8; ++n) acc[m][n] = (f4v){0.f,0.f,0.f,0.f};
  for (int n = 0; n < 8; ++n){
    int G = n*16 + l15;
    bf8v b[4];
    #pragma unroll
    for (int ksi = 0; ksi < 4; ++ksi)
      b[ksi] = *reinterpret_cast<const bf8v*>(Wo + G*128 + ksi*32 + quad*8);
    #pragma unroll
    for (int m = 0; m < 2; ++m)
      #pragma unroll
      for (int ksi = 0; ksi < 4; ++ksi)
        acc[m][n] = mfma16(a[m][ksi], b[ksi], acc[m][n]);
  }
  __syncthreads();   // h0 staged & visible
  #pragma unroll
  for (int m = 0; m < 2; ++m){
    #pragma unroll
    for (int n = 0; n < 8; ++n){
      int col = n*16 + l15;
      float bia = b2f(bo[col]);
      #pragma unroll
      for (int r = 0; r < 4; ++r){
        int lrow = m0 + m*16 + quad*4 + r;
        acc[m][n][r] += bia + s2f(atile[lrow*136 + col]);
      }
    }
    float sm[4], sq[4];
    #pragma unroll
    for (int r = 0; r < 4; ++r){ sm[r] = 0.f; sq[r] = 0.f; }
    #pragma unroll
    for (int n = 0; n < 8; ++n)
      #pragma unroll
      for (int r = 0; r < 4; ++r){
        float v = acc[m][n][r];
        sm[r] += v; sq[r] += v*v;
      }
    #pragma unroll
    for (int mask = 1; mask < 16; mask <<= 1)
      #pragma unroll
      for (int r = 0; r < 4; ++r){
        sm[r] += __shfl_xor(sm[r], mask);
        sq[r] += __shfl_xor(sq[r], mask);
      }
    float mean[4], rs[4];
    #pragma unroll
    for (int r = 0; r < 4; ++r){
      mean[r] = sm[r]*(1.0f/128.0f);
      float var = fmaxf(sq[r]*(1.0f/128.0f) - mean[r]*mean[r], 0.0f);
      rs[r] = rsqrtf(var + 1e-5f);
    }
    #pragma unroll
    for (int n = 0; n < 8; ++n){
      int col = n*16 + l15;
      float gv = b2f(ga[col]), bv = b2f(ba_[col]);
      #pragma unroll
      for (int r = 0; r < 4; ++r){
        int lrow = m0 + m*16 + quad*4 + r;
        float y = (acc[m][n][r] - mean[r])*rs[r]*gv + bv;
        atile[lrow*136 + col] = f2bs(y);
      }
    }
  }
  __syncthreads();
  {
    uint4* dst = (uint4*)(h1 + rt*16384);
    const uint4* src = (const uint4*)atile;
    for (int u = tid; u < 2048; u += 256){
      int r = u >> 4, c = u & 15;
      dst[u] = src[r*17 + c];
    }
  }
}

// ---------------------------------------------------------------------------
// K5: fused forward LSTM + backward single-step + temporal projection.
// grid = 100, block = 512 (8 waves). exp2-prescaled weights + packed gates.
// ---------------------------------------------------------------------------
__global__ __launch_bounds__(512,1) void k_lstm(const bf16* __restrict__ Whh_s,
    const bf16* __restrict__ Wih_s, const float* __restrict__ bias_s,
    const bf16* __restrict__ h1,
    const bf16* __restrict__ Wihb, const bf16* __restrict__ bihb,
    const bf16* __restrict__ bhhb, const bf16* __restrict__ Wtp,
    const bf16* __restrict__ btp, bf16* __restrict__ ht_pad,
    const int* __restrict__ flag, bf16* __restrict__ outb,
    float* __restrict__ outf){
  int bn0 = blockIdx.x * 16;
  int tid = threadIdx.x;
  int w = tid >> 6, lane = tid & 63;
  int l15 = lane & 15, quad = lane >> 4;
  __shared__ __align__(16) short hbuf[2][16*136];
  __shared__ __align__(16) short xbuf[2][16*136];
  __shared__ __align__(16) short ycat[16*264];

  bf8v whh[4][4], wih[4][4];
  float bs[4];
  #pragma unroll
  for (int role = 0; role < 4; ++role){
    int G = role*128 + w*16 + l15;
    #pragma unroll
    for (int kt = 0; kt < 4; ++kt){
      whh[role][kt] = *reinterpret_cast<const bf8v*>(Whh_s + G*128 + kt*32 + quad*8);
      wih[role][kt] = *reinterpret_cast<const bf8v*>(Wih_s + G*128 + kt*32 + quad*8);
    }
    bs[role] = bias_s[G];
  }
  const uint4* h1u4 = (const uint4*)h1;
  int srow = tid >> 4, scol = tid & 15;

  for (int i = tid; i < 16*136; i += 512) hbuf[0][i] = 0;
  if (tid < 256)
    ((uint4*)xbuf[0])[srow*17 + scol] = h1u4[((bn0 + srow)*96 + 0)*16 + scol];
  f4v c0 = {0.f,0.f,0.f,0.f};
  uint4 xpre;
  if (tid < 256) xpre = h1u4[((bn0 + srow)*96 + 1)*16 + scol];
  __syncthreads();

  f4v accx[4];
  {
    bf8v ax[4];
    #pragma unroll
    for (int kt = 0; kt < 4; ++kt)
      ax[kt] = *reinterpret_cast<const bf8v*>(xbuf[0] + l15*136 + kt*32 + quad*8);
    #pragma unroll
    for (int role = 0; role < 4; ++role){
      f4v z = {bs[role], bs[role], bs[role], bs[role]};
      #pragma unroll
      for (int kt = 0; kt < 4; ++kt) z = mfma16(ax[kt], wih[role][kt], z);
      accx[role] = z;
    }
  }
  if (tid < 256) ((uint4*)xbuf[1])[srow*17 + scol] = xpre;
  if (tid < 256) xpre = h1u4[((bn0 + srow)*96 + 2)*16 + scol];
  __syncthreads();

  int colw = w*16 + l15;
  for (int t = 0; t < 96; ++t){
    int cur = t & 1, nxt = cur ^ 1;
    bf8v ah[4], axn[4];
    #pragma unroll
    for (int kt = 0; kt < 4; ++kt){
      ah[kt]  = *reinterpret_cast<const bf8v*>(hbuf[cur] + l15*136 + kt*32 + quad*8);
      axn[kt] = *reinterpret_cast<const bf8v*>(xbuf[nxt] + l15*136 + kt*32 + quad*8);
    }
    f4v acc[4];
    #pragma unroll
    for (int role = 0; role < 4; ++role){
      f4v z = accx[role];
      #pragma unroll
      for (int kt = 0; kt < 4; ++kt) z = mfma16(ah[kt], whh[role][kt], z);
      acc[role] = z;
    }
    #pragma unroll
    for (int role = 0; role < 4; ++role){
      f4v z = {bs[role], bs[role], bs[role], bs[role]};
      #pragma unroll
      for (int kt = 0; kt < 4; ++kt) z = mfma16(axn[kt], wih[role][kt], z);
      accx[role] = z;
    }
    #pragma unroll
    for (int p = 0; p < 2; ++p){
      int r0 = 2*p, r1 = 2*p + 1;
      f2v ai = pk2(acc[0][r0], acc[0][r1]);
      f2v af = pk2(acc[1][r0], acc[1][r1]);
      f2v ag = pk2(acc[2][r0], acc[2][r1]);
      f2v ao = pk2(acc[3][r0], acc[3][r1]);
      f2v ei = pkexp2(pkmin(ai, 40.0f));
      f2v ef = pkexp2(pkmin(af, 40.0f));
      f2v eg = pkexp2(pkmin(pkmax(ag, -40.0f), 40.0f));
      f2v eo = pkexp2(pkmin(ao, 40.0f));
      f2v one = pk2(1.0f, 1.0f);
      f2v Bi = one + ei, Cg = one + eg, Af = one + ef;
      f2v BC = Bi*Cg;
      f2v cs = pk2(c0[r0], c0[r1]);
      f2v cn = cs*BC + (one - eg)*Af;
      f2v c  = cn * pkrcp(Af*BC);
      c0[r0] = c[0]; c0[r1] = c[1];
      f2v cc = pkmin(pkmax(c * -2.88539008178f, -40.0f), 40.0f);
      f2v ec = pkexp2(cc);
      f2v hv = (one - ec) * pkrcp((one + eo)*(one + ec));
      hbuf[nxt][(quad*4 + r0)*136 + colw] = f2bs(hv[0]);
      hbuf[nxt][(quad*4 + r1)*136 + colw] = f2bs(hv[1]);
    }
    if (tid < 256){
      ((uint4*)xbuf[cur])[srow*17 + scol] = xpre;
      int tl = (t + 3 < 96) ? t + 3 : 95;
      xpre = h1u4[((bn0 + srow)*96 + tl)*16 + scol];
    }
    __syncthreads();
  }
  // ---- epilogue: bwd single-step (zero state, x_95 in xbuf[0]) + Wtp ----
  for (int idx = tid; idx < 2048; idx += 512){
    int r = idx >> 7, d = idx & 127;
    ycat[r*264 + d] = hbuf[0][r*136 + d];
  }
  {
    bf8v ax[4];
    #pragma unroll
    for (int kt = 0; kt < 4; ++kt)
      ax[kt] = *reinterpret_cast<const bf8v*>(xbuf[0] + l15*136 + kt*32 + quad*8);
    int col = w*16 + l15;
    f4v gi = {0.f,0.f,0.f,0.f}, gg = {0.f,0.f,0.f,0.f}, go = {0.f,0.f,0.f,0.f};
    #pragma unroll
    for (int kt = 0; kt < 4; ++kt){
      gi = mfma16(ax[kt], *reinterpret_cast<const bf8v*>(Wihb + col*128 + kt*32 + quad*8), gi);
      gg = mfma16(ax[kt], *reinterpret_cast<const bf8v*>(Wihb + (256 + col)*128 + kt*32 + quad*8), gg);
      go = mfma16(ax[kt], *reinterpret_cast<const bf8v*>(Wihb + (384 + col)*128 + kt*32 + quad*8), go);
    }
    float bi = b2f(bihb[col])       + b2f(bhhb[col]);
    float bg = b2f(bihb[256 + col]) + b2f(bhhb[256 + col]);
    float bo = b2f(bihb[384 + col]) + b2f(bhhb[384 + col]);
    #pragma unroll
    for (int r = 0; r < 4; ++r){
      float c  = sigf(gi[r] + bi) * tanhfast(gg[r] + bg);
      float yb = sigf(go[r] + bo) * tanhfast(c);
      ycat[(quad*4 + r)*264 + 128 + col] = f2bs(yb);
    }
  }
  __syncthreads();
  {
    int col = w*16 + l15;
    f4v z = {0.f,0.f,0.f,0.f};
    #pragma unroll
    for (int kt = 0; kt < 8; ++kt){
      bf8v a = *reinterpret_cast<const bf8v*>(ycat + l15*264 + kt*32 + quad*8);
      bf8v bb = *reinterpret_cast<const bf8v*>(Wtp + col*256 + kt*32 + quad*8);
      z = mfma16(a, bb, z);
    }
    float bt = b2f(btp[col]);
    #pragma unroll
    for (int r = 0; r < 4; ++r){
      int rowg = bn0 + quad*4 + r;
      float v = z[r] + bt;
      int bb_ = rowg/100, nn = rowg - bb_*100;
      ht_pad[(bb_*112 + nn)*128 + col] = f2b(v);
      int oi = 206400 + rowg*128 + col;
      if (flag[0]) outb[oi] = f2b(v); else outf[oi] = v;
    }
  }
}

// ---------------------------------------------------------------------------
// K_SPAT: fused spatial pipeline (spat1 + spat2). grid = 16, block = 512.
// ---------------------------------------------------------------------------
__global__ __launch_bounds__(512,1) void k_spat(
    const bf16* __restrict__ ht_pad, const bf16* __restrict__ Hinc,
    const bf16* __restrict__ Wn, const bf16* __restrict__ bn_,
    const bf16* __restrict__ We, const bf16* __restrict__ be,
    const bf16* __restrict__ Wa, const bf16* __restrict__ ba,
    const bf16* __restrict__ gg_, const bf16* __restrict__ bg_,
    bf16* __restrict__ hb2g, const bf16* __restrict__ Anp,
    const bf16* __restrict__ Wg, const bf16* __restrict__ bgc,
    const bf16* __restrict__ Remb, const int* __restrict__ mem,
    const bf16* __restrict__ Wf, const bf16* __restrict__ bf_,
    const bf16* __restrict__ gf, const bf16* __restrict__ b_f,
    const bf16* __restrict__ W1, const bf16* __restrict__ b1,
    const bf16* __restrict__ W2, const bf16* __restrict__ b2,
    const int* __restrict__ flag, bf16* __restrict__ outb,
    float* __restrict__ outf){
  int b = blockIdx.x, tid = threadIdx.x;
  int w = tid >> 6, lane = tid & 63, l15 = lane & 15, quad = lane >> 4;
  __shared__ __align__(16) short htb[112*136];
  __shared__ __align__(16) short mtile[16*136];
  __shared__ float HincS[1600];
  __shared__ float wts[1600];
  __shared__ float eeS[16*128];
  __shared__ float scE[16], degS[16], part[128];
  __shared__ __align__(16) short regA[128*136];
  __shared__ __align__(16) short regB[112*136];

  // ================= phase A: hyperedge attention + node LN =================
  {
    const uint4* src = (const uint4*)(ht_pad + b*14336);
    uint4* dst = (uint4*)htb;
    for (int u = tid; u < 1792; u += 512){
      int r = u >> 4, c = u & 15;
      dst[r*17 + c] = src[u];
    }
  }
  for (int i = tid; i < 1600; i += 512) HincS[i] = b2f(Hinc[i]);
  __syncthreads();
  if (tid < 16){
    float s = 0.0f;
    for (int n = 0; n < 100; ++n) s += HincS[n*16 + tid];
    degS[tid] = s;
  }
  __syncthreads();
  for (int it = 0; it < 4; ++it){
    int idx = tid + it*512;
    int e = idx >> 7, d = idx & 127;
    float s = 0.0f;
    for (int n = 0; n < 100; ++n)
      s += HincS[n*16 + e] * s2f(htb[n*136 + d]);
    mtile[e*136 + d] = f2bs(s * rcpf_(degS[e] + 1e-8f));
  }
  __syncthreads();
  {
    bf8v a[4];
    #pragma unroll
    for (int kt = 0; kt < 4; ++kt)
      a[kt] = *reinterpret_cast<const bf8v*>(mtile + l15*136 + kt*32 + quad*8);
    int col = w*16 + l15;
    f4v z = {0.f,0.f,0.f,0.f};
    #pragma unroll
    for (int kt = 0; kt < 4; ++kt)
      z = mfma16(a[kt], *reinterpret_cast<const bf8v*>(Wn + col*128 + kt*32 + quad*8), z);
    float bnv = b2f(bn_[col]);
    __syncthreads();
    #pragma unroll
    for (int r = 0; r < 4; ++r){
      int e = quad*4 + r;
      float ratio = degS[e] * rcpf_(degS[e] + 1e-8f);
      mtile[e*136 + col] = f2bs(z[r] + bnv*ratio);
    }
  }
  __syncthreads();
  {
    bf8v a[4];
    #pragma unroll
    for (int kt = 0; kt < 4; ++kt)
      a[kt] = *reinterpret_cast<const bf8v*>(mtile + l15*136 + kt*32 + quad*8);
    int col = w*16 + l15;
    f4v z = {0.f,0.f,0.f,0.f};
    #pragma unroll
    for (int kt = 0; kt < 4; ++kt)
      z = mfma16(a[kt], *reinterpret_cast<const bf8v*>(We + col*128 + kt*32 + quad*8), z);
    float bev = b2f(be[col]);
    #pragma unroll
    for (int r = 0; r < 4; ++r)
      eeS[(quad*4 + r)*128 + col] = z[r] + bev;
  }
  __syncthreads();
  if (tid < 128){
    int e = tid >> 3, j = tid & 7;
    float s = 0.0f;
    for (int d = j*16; d < j*16 + 16; ++d)
      s += eeS[e*128 + d] * b2f(Wa[d]);
    part[tid] = s;
  }
  __syncthreads();
  if (tid < 16){
    float s = b2f(ba[0]);
    for (int j = 0; j < 8; ++j) s += part[tid*8 + j];
    scE[tid] = s;
  }
  __syncthreads();
  if (tid < 100){
    float sc[16], mx = -1e30f;
    for (int e = 0; e < 16; ++e){
      sc[e] = (HincS[tid*16 + e] > 0.0f) ? scE[e] : -1e30f;
      mx = fmaxf(mx, sc[e]);
    }
    float sum = 0.0f, tmp[16];
    for (int e = 0; e < 16; ++e){
      tmp[e] = (sc[e] > -1e29f) ? __expf(sc[e] - mx) : 0.0f;
      sum += tmp[e];
    }
    float inv = (sum > 0.0f) ? rcpf_(sum) : 0.0f;
    for (int e = 0; e < 16; ++e) wts[tid*16 + e] = tmp[e]*inv;
  }
  __syncthreads();
  for (int it = 0; it < 13; ++it){
    int n = it*8 + w;
    if (n < 100){
      int d0 = lane*2;
      float s0 = s2f(htb[n*136 + d0]);
      float s1 = s2f(htb[n*136 + d0 + 1]);
      for (int e = 0; e < 16; ++e){
        float wv = wts[n*16 + e];
        s0 += wv * eeS[e*128 + d0];
        s1 += wv * eeS[e*128 + d0 + 1];
      }
      float sum = s0 + s1, sq = s0*s0 + s1*s1;
      #pragma unroll
      for (int mask = 1; mask < 64; mask <<= 1){
        sum += __shfl_xor(sum, mask);
        sq  += __shfl_xor(sq, mask);
      }
      float mean = sum*(1.0f/128.0f);
      float var = fmaxf(sq*(1.0f/128.0f) - mean*mean, 0.0f);
      float rs = rsqrtf(var + 1e-5f);
      float y0 = (s0 - mean)*rs*b2f(gg_[d0])     + b2f(bg_[d0]);
      float y1 = (s1 - mean)*rs*b2f(gg_[d0 + 1]) + b2f(bg_[d0 + 1]);
      hb2g[b*14336 + n*128 + d0]     = f2b(y0);
      hb2g[b*14336 + n*128 + d0 + 1] = f2b(y1);
    }
  }
  __syncthreads();   // hb2g writes drained before phase B reads

  // ================= phase B: GCN + fusion + head =================
  for (int i = tid; i < 128*136; i += 512) regA[i] = 0;
  __syncthreads();
  {
    int c0 = w*16;
    bf8v bw[4];
    #pragma unroll
    for (int kt = 0; kt < 4; ++kt)
      bw[kt] = *reinterpret_cast<const bf8v*>(Wg + (c0 + l15)*128 + kt*32 + quad*8);
    for (int m = 0; m < 7; ++m){
      f4v z = {0.f,0.f,0.f,0.f};
      #pragma unroll
      for (int kt = 0; kt < 4; ++kt){
        bf8v a = *reinterpret_cast<const bf8v*>(hb2g + b*14336 + (m*16 + l15)*128 + kt*32 + quad*8);
        z = mfma16(a, bw[kt], z);
      }
      s4v vs;
      #pragma unroll
      for (int r = 0; r < 4; ++r) vs[r] = f2bs(z[r]);
      *reinterpret_cast<s4v*>(regA + (c0 + l15)*136 + m*16 + quad*4) = vs;
    }
  }
  __syncthreads();
  {
    int c0 = w*16;
    for (int m = 0; m < 7; ++m){
      f4v z = {0.f,0.f,0.f,0.f};
      #pragma unroll
      for (int kt = 0; kt < 4; ++kt){
        bf8v a  = *reinterpret_cast<const bf8v*>(Anp + (m*16 + l15)*128 + kt*32 + quad*8);
        bf8v bb = *reinterpret_cast<const bf8v*>(regA + (c0 + l15)*136 + kt*32 + quad*8);
        z = mfma16(a, bb, z);
      }
      #pragma unroll
      for (int r = 0; r < 4; ++r){
        int row = m*16 + quad*4 + r, col = c0 + l15;
        if (row < 100){
          float v = fmaxf(z[r] + b2f(bgc[col]), 0.0f);
          float o = b2f(hb2g[b*14336 + row*128 + col]) + v
                  + b2f(Remb[mem[row]*128 + col]);
          int oi = 1600 + (b*100 + row)*128 + col;
          if (flag[0]) outb[oi] = f2b(o); else outf[oi] = o;
          regB[row*136 + col] = f2bs(o);
        } else {
          regB[row*136 + col] = 0;
        }
      }
    }
  }
  __syncthreads();
  if (w < 7){
    int m = w;
    f4v acc[8];
    for (int n = 0; n < 8; ++n){
      f4v z = {0.f,0.f,0.f,0.f};
      #pragma unroll
      for (int kt = 0; kt < 4; ++kt){
        bf8v a  = *reinterpret_cast<const bf8v*>(htb + (m*16 + l15)*136 + kt*32 + quad*8);
        bf8v bb = *reinterpret_cast<const bf8v*>(Wf + (n*16 + l15)*256 + kt*32 + quad*8);
        z = mfma16(a, bb, z);
      }
      #pragma unroll
      for (int kt = 0; kt < 4; ++kt){
        bf8v a  = *reinterpret_cast<const bf8v*>(regB + (m*16 + l15)*136 + kt*32 + quad*8);
        bf8v bb = *reinterpret_cast<const bf8v*>(Wf + (n*16 + l15)*256 + 128 + kt*32 + quad*8);
        z = mfma16(a, bb, z);
      }
      acc[n] = z;
    }
    float sm[4], sq[4];
    #pragma unroll
    for (int r = 0; r < 4; ++r){ sm[r] = 0.f; sq[r] = 0.f; }
    #pragma unroll
    for (int n = 0; n < 8; ++n){
      int col = n*16 + l15;
      float bv = b2f(bf_[col]);
      #pragma unroll
      for (int r = 0; r < 4; ++r){
        float v = acc[n][r] + bv;
        acc[n][r] = v;
        sm[r] += v; sq[r] += v*v;
      }
    }
    #pragma unroll
    for (int mask = 1; mask < 16; mask <<= 1)
      #pragma unroll
      for (int r = 0; r < 4; ++r){
        sm[r] += __shfl_xor(sm[r], mask);
        sq[r] += __shfl_xor(sq[r], mask);
      }
    #pragma unroll
    for (int r = 0; r < 4; ++r){
      float mean = sm[r]*(1.0f/128.0f);
      float var = fmaxf(sq[r]*(1.0f/128.0f) - mean*mean, 0.0f);
      float rs = rsqrtf(var + 1e-5f);
      #pragma unroll
      for (int n = 0; n < 8; ++n){
        int col = n*16 + l15;
        float y = fmaxf((acc[n][r] - mean)*rs*b2f(gf[col]) + b2f(b_f[col]), 0.0f);
        regA[(m*16 + quad*4 + r)*136 + col] = f2bs(y);
      }
    }
  }
  __syncthreads();
  if (w < 7){
    int m = w;
    for (int n = 0; n < 4; ++n){
      f4v z = {0.f,0.f,0.f,0.f};
      #pragma unroll
      for (int kt = 0; kt < 4; ++kt){
        bf8v a  = *reinterpret_cast<const bf8v*>(regA + (m*16 + l15)*136 + kt*32 + quad*8);
        bf8v bb = *reinterpret_cast<const bf8v*>(W1 + (n*16 + l15)*128 + kt*32 + quad*8);
        z = mfma16(a, bb, z);
      }
      #pragma unroll
      for (int r = 0; r < 4; ++r){
        int row = m*16 + quad*4 + r, col = n*16 + l15;
        regB[row*72 + col] = f2bs(fmaxf(z[r] + b2f(b1[col]), 0.0f));
      }
    }
  }
  __syncthreads();
  if (tid < 100){
    float s = b2f(b2[0]);
    for (int d = 0; d < 64; ++d)
      s += s2f(regB[tid*72 + d]) * b2f(W2[d]);
    int oi = b*100 + tid;
    if (flag[0]) outb[oi] = f2b(s); else outf[oi] = s;
  }
}

// ---------------------------------------------------------------------------

extern "C" void kernel_launch(void* const* d_in, const int* in_sizes, int n_in,
                              void* d_out, int out_size, void* d_ws, size_t ws_size,
                              hipStream_t stream){
  (void)n_in; (void)out_size; (void)ws_size;
  const int* mem = (const int*)d_in[3];

  CArgs ca;
  int coff[43];
  int nf = 0;
  long long off = 0;
  for (int i = 0; i < 43; ++i){
    if (i == 3){ coff[i] = -1; continue; }
    coff[i] = (int)off;
    ca.src[nf] = d_in[i];
    ca.n[nf]   = in_sizes[i];
    ca.off[nf] = (int)off;
    ++nf;
    off += (long long)((in_sizes[i] + 7) & ~7);
  }
  char* ws = (char*)d_ws;
  bf16* canon = (bf16*)ws;
  long long canonBytes = ((off*2 + 255)/256)*256;
  int* flag = (int*)(ws + canonBytes);
  long long base = canonBytes + 256;

  #define C(i) (canon + coff[i])
  const bf16* Hinc   = C(2);
  const bf16* bp  = C(5);
  const bf16* g_p = C(6);  const bf16* b_p = C(7);
  const bf16* Wqkv= C(8);  const bf16* bqkv= C(9);
  const bf16* Wo  = C(10); const bf16* bo  = C(11);
  const bf16* g_a = C(12); const bf16* b_a = C(13);
  const bf16* Wih_b = C(18);
  const bf16* bih_b = C(20); const bf16* bhh_b = C(21);
  const bf16* Wtp = C(22); const bf16* btp = C(23);
  const bf16* Wn  = C(24); const bf16* bn_ = C(25);
  const bf16* We  = C(26); const bf16* be  = C(27);
  const bf16* Wa  = C(28); const bf16* ba  = C(29);
  const bf16* g_g = C(30); const bf16* b_g = C(31);
  const bf16* Remb= C(32);
  const bf16* Wg  = C(33); const bf16* bg  = C(34);
  const bf16* Wf  = C(35); const bf16* bff = C(36);
  const bf16* g_f = C(37); const bf16* b_f = C(38);
  const bf16* W1  = C(39); const bf16* b1  = C(40);
  const bf16* W2  = C(41); const bf16* b2  = C(42);
  const bf16* xc  = C(0);
  #undef C

  bf16*  outb = (bf16*)d_out;
  float* outf = (float*)d_out;
  bf16*  h1     = (bf16*)(ws + base);                 // 39,321,600 B
  bf16*  h0     = (bf16*)(ws + base + 39321600LL);    // 39,321,600 B
  bf16*  attno  = (bf16*)(ws + base + 78643200LL);    // 39,321,600 B
  bf16*  Wpp    = (bf16*)(ws + base + 196608000LL);   // 8192 B
  bf16*  An_pad = (bf16*)(ws + base + 196616192LL);   // 28672 B
  bf16*  ht_pad = (bf16*)(ws + base + 196644864LL);   // 458752 B
  bf16*  hb2g   = (bf16*)(ws + base + 197103616LL);   // 458752 B
  bf16*  Whh_s  = (bf16*)(ws + base + 197562368LL);   // 131072 B
  bf16*  Wih_s  = (bf16*)(ws + base + 197693440LL);   // 131072 B
  float* bias_s = (float*)(ws + base + 197824512LL);  // 2048 B

  k_pre   <<<dim3(64, nf + 1), 256, 0, stream>>>(ca, nf,
                                     (const unsigned int*)d_in[0],
                                     d_in[4], d_in[1], d_in[15], d_in[14],
                                     d_in[16], d_in[17],
                                     canon, flag,
                                     Wpp, An_pad, ht_pad, hb2g,
                                     Whh_s, Wih_s, bias_s);
  k_inat  <<<1600, 256, 0, stream>>>(xc, Wpp, bp, g_p, b_p, Wqkv, bqkv,
                                     h0, attno);
  k_oproj <<<1200, 256, 0, stream>>>(attno, h0, Wo, bo, g_a, b_a, h1);
  k_lstm  <<<100,  512, 0, stream>>>(Whh_s, Wih_s, bias_s, h1,
                                     Wih_b, bih_b, bhh_b, Wtp, btp, ht_pad,
                                     flag, outb, outf);
  k_spat  <<<16,   512, 0, stream>>>(ht_pad, Hinc, Wn, bn_, We, be, Wa, ba,
                                     g_g, b_g, hb2g, An_pad, Wg, bg, Remb, mem,
                                     Wf, bff, g_f, b_f, W1, b1, W2, b2,
                                     flag, outb, outf);
}